// Round 15
// baseline (671.946 us; speedup 1.0000x reference)
//
#include <hip/hip_runtime.h>

constexpr int NN   = 250000;      // nodes
constexpr int NE   = 1000000;     // edges
constexpr int NBm  = 25;          // graphs
constexpr int BSg  = NN / NBm;    // 10000 nodes per graph
constexpr int NCc  = 72;          // voxel cells per graph
constexpr int MM   = NBm * NCc;   // 1800 pooled slots
constexpr int PRES = NBm * NCc * NCc; // 129600 coarse-edge presence slots
constexpr int NBK  = NBm * 16;    // 400 sort buckets: graph*16 + (15 - min(deg,15))  [descending]
constexpr float EPSbn = 1e-5f;

// ---------------- graph prep ----------------

__global__ __launch_bounds__(256) void k_deg(const int* __restrict__ dst, int* __restrict__ deg, int n) {
    int e = blockIdx.x * 256 + threadIdx.x;
    if (e < n) atomicAdd(&deg[dst[e]], 1);
}

// per-block LDS histogram over 400 (graph,deg) buckets -> low-contention global adds
__global__ __launch_bounds__(256) void k_dhist(const int* __restrict__ deg, const int* __restrict__ batch,
                                               int* __restrict__ dhist, int n) {
    __shared__ int h[NBK];
    int tid = threadIdx.x;
    for (int i = tid; i < NBK; i += 256) h[i] = 0;
    __syncthreads();
    int i = blockIdx.x * 256 + tid;
    if (i < n) atomicAdd(&h[batch[i] * 16 + (15 - min(deg[i], 15))], 1);
    __syncthreads();
    for (int b = tid; b < NBK; b += 256) if (h[b]) atomicAdd(&dhist[b], h[b]);
}

__global__ __launch_bounds__(256) void k_dscan(const int* __restrict__ dhist, int* __restrict__ dcur) {
    __shared__ int tmp[NBK];
    int t = threadIdx.x;
    for (int i = t; i < NBK; i += 256) tmp[i] = dhist[i];
    __syncthreads();
    if (t == 0) { int run = 0; for (int i = 0; i < NBK; i++) { int v = tmp[i]; tmp[i] = run; run += v; } }
    __syncthreads();
    for (int i = t; i < NBK; i += 256) dcur[i] = tmp[i];
}

// two-phase scatter: LDS local ranks + one ranged global atomicAdd per (block,bucket).
__global__ __launch_bounds__(256) void k_dscat(const int* __restrict__ deg, const int* __restrict__ batch,
                                               const float* __restrict__ x_in,
                                               int* __restrict__ dcur, int* __restrict__ pinv,
                                               int* __restrict__ deg_p, float* __restrict__ xin_p, int n) {
    __shared__ int lcnt[NBK];
    __shared__ int gbase[NBK];
    int tid = threadIdx.x;
    for (int i = tid; i < NBK; i += 256) lcnt[i] = 0;
    __syncthreads();
    int i = blockIdx.x * 256 + tid;
    int b = 0, rank = 0;
    if (i < n) {
        b = batch[i] * 16 + (15 - min(deg[i], 15));
        rank = atomicAdd(&lcnt[b], 1);
    }
    __syncthreads();
    for (int k = tid; k < NBK; k += 256)
        if (lcnt[k]) gbase[k] = atomicAdd(&dcur[k], lcnt[k]);
    __syncthreads();
    if (i < n) {
        int slot = gbase[b] + rank;
        pinv[i] = slot;
        deg_p[slot] = deg[i];
        xin_p[slot] = x_in[i];
    }
}

__global__ __launch_bounds__(256) void k_scan1(const int* __restrict__ in, int n,
                                               int* __restrict__ outEx, int* __restrict__ bsum) {
    __shared__ int lds[256];
    int t = threadIdx.x;
    int base = blockIdx.x * 2048;
    int v[8]; int s = 0;
#pragma unroll
    for (int i = 0; i < 8; i++) { int idx = base + t * 8 + i; v[i] = (idx < n) ? in[idx] : 0; s += v[i]; }
    lds[t] = s; __syncthreads();
    for (int o = 1; o < 256; o <<= 1) {
        int x = (t >= o) ? lds[t - o] : 0; __syncthreads();
        lds[t] += x; __syncthreads();
    }
    if (t == 255) bsum[blockIdx.x] = lds[255];
    int run = lds[t] - s;
#pragma unroll
    for (int i = 0; i < 8; i++) { int idx = base + t * 8 + i; if (idx < n) outEx[idx] = run; run += v[i]; }
}

__global__ __launch_bounds__(256) void k_scan2(int* bsum, int nb) {
    __shared__ int l[256];
    int t = threadIdx.x;
    int v = (t < nb) ? bsum[t] : 0;
    l[t] = v; __syncthreads();
    for (int o = 1; o < 256; o <<= 1) {
        int x = (t >= o) ? l[t - o] : 0; __syncthreads();
        l[t] += x; __syncthreads();
    }
    if (t < nb) bsum[t] = l[t] - v;   // exclusive
}

__global__ __launch_bounds__(256) void k_scan3(int* __restrict__ outEx, int n, const int* __restrict__ bsum) {
    int i = blockIdx.x * 256 + threadIdx.x;
    if (i < n) outEx[i] += bsum[i >> 11];
}

// LDS-staged cluster assignment + per-cell count/pos sums (R13: 75us -> ~8us).
__global__ __launch_bounds__(256) void k_cluster(const float* __restrict__ pos, const int* __restrict__ pinv,
                                                 int* __restrict__ cluster, int* __restrict__ cluster_p,
                                                 int* __restrict__ cnt, float* __restrict__ ppsum) {
    __shared__ int lcnt[NCc];
    __shared__ float lpp[NCc * 3];
    int tid = threadIdx.x;
    int g = blockIdx.x >> 3, part = blockIdx.x & 7;
    for (int i = tid; i < NCc; i += 256) lcnt[i] = 0;
    for (int i = tid; i < NCc * 3; i += 256) lpp[i] = 0.f;
    __syncthreads();
    int base = g * BSg + part * (BSg / 8);
    int lim = BSg / 8;
    for (int k = tid; k < lim; k += 256) {
        int i = base + k;
        float px = pos[i * 3], py = pos[i * 3 + 1], pz = pos[i * 3 + 2];
        int cx = min(max((int)floorf(px / 16.f), 0), 7);
        int cy = min(max((int)floorf(py / 12.f), 0), 8);
        int lc = cy * 8 + cx;
        cluster[i] = g * NCc + lc;
        cluster_p[pinv[i]] = g * NCc + lc;
        atomicAdd(&lcnt[lc], 1);
        atomicAdd(&lpp[lc * 3 + 0], px);
        atomicAdd(&lpp[lc * 3 + 1], py);
        atomicAdd(&lpp[lc * 3 + 2], pz);
    }
    __syncthreads();
    for (int c = tid; c < NCc; c += 256) {
        if (lcnt[c]) {
            atomicAdd(&cnt[g * NCc + c], lcnt[c]);
            atomicAdd(&ppsum[(g * NCc + c) * 3 + 0], lpp[c * 3 + 0]);
            atomicAdd(&ppsum[(g * NCc + c) * 3 + 1], lpp[c * 3 + 1]);
            atomicAdd(&ppsum[(g * NCc + c) * 3 + 2], lpp[c * 3 + 2]);
        }
    }
}

// Fused: edge record scatter (CSR by permuted dst) + coarse-edge presence map.
// One pass over src/dst instead of two.
__global__ __launch_bounds__(256) void k_scatter(const int* __restrict__ src, const int* __restrict__ dst,
                                                 const float* __restrict__ ea, const int* __restrict__ offx,
                                                 const int* __restrict__ pinv, const int* __restrict__ cluster,
                                                 int* __restrict__ cursor, float4* __restrict__ erec,
                                                 unsigned char* __restrict__ presence, int n) {
    int e = blockIdx.x * 256 + threadIdx.x;
    if (e >= n) return;
    int s = src[e], d = dst[e];
    int pd = pinv[d];
    int j = offx[pd] + atomicAdd(&cursor[pd], 1);
    float p0 = fminf(fmaxf(ea[e * 3 + 0], 0.f), 1.f);
    float p1 = fminf(fmaxf(ea[e * 3 + 1], 0.f), 1.f);
    float p2 = fminf(fmaxf(ea[e * 3 + 2], 0.f), 1.f);
    erec[j] = make_float4(__int_as_float(pinv[s]), p0, p1, p2);
    int r = cluster[s], c = cluster[d];
    if (r != c) {
        int g = r / NCc;
        presence[g * (NCc * NCc) + (r % NCc) * NCc + (c % NCc)] = 1;
    }
}

__global__ __launch_bounds__(256) void k_fpp(const int* __restrict__ cnt, const float* __restrict__ ppsum,
                                             float* __restrict__ pp, int* __restrict__ nmask, int* __restrict__ nmc) {
    int m = blockIdx.x * 256 + threadIdx.x;
    if (m >= MM) return;
    int c = cnt[m];
    float inv = 1.f / (float)max(c, 1);
    pp[m * 3 + 0] = ppsum[m * 3 + 0] * inv;
    pp[m * 3 + 1] = ppsum[m * 3 + 1] * inv;
    pp[m * 3 + 2] = ppsum[m * 3 + 2] * inv;
    nmask[m] = (c > 0);
    if (c > 0) atomicAdd(nmc, 1);
}

__global__ __launch_bounds__(256) void k_maxv(const unsigned char* __restrict__ presence, const float* __restrict__ pp,
                                              float* __restrict__ maxv) {
    int i = blockIdx.x * 256 + threadIdx.x;
    float m = 0.f;
    if (i < PRES && presence[i]) {
        int g = i / (NCc * NCc), rem = i % (NCc * NCc);
        int r = g * NCc + rem / NCc, c = g * NCc + rem % NCc;
        float d0 = fabsf(pp[c * 3 + 0] - pp[r * 3 + 0]);
        float d1 = fabsf(pp[c * 3 + 1] - pp[r * 3 + 1]);
        float d2 = fabsf(pp[c * 3 + 2] - pp[r * 3 + 2]);
        m = fmaxf(fmaxf(d0, d1), d2);
    }
    for (int o = 32; o; o >>= 1) m = fmaxf(m, __shfl_xor(m, o));
    if ((threadIdx.x & 63) == 0) atomicMax((int*)maxv, __float_as_int(m));
}

// ---------------- full-graph spline conv ----------------
// Mirror-paired balanced waves (R=2), depth-1 pipelined branchless edge loop
// (R12's measured-best 74us), 128-thread blocks (2 waves) for finer
// block-granularity scheduling (shorter drain tail at equal per-CU capacity).

template <int CIN, int COUT, int TPN, bool BN>
__global__ __launch_bounds__(128) void k_conv(
    const float* __restrict__ x, const float4* __restrict__ erec,
    const int* __restrict__ off, const int* __restrict__ deg,
    const float* __restrict__ W, const float* __restrict__ st,
    const float* __restrict__ gam, const float* __restrict__ bet, float invcnt,
    float* __restrict__ out, float* __restrict__ stG, int nwaves) {
    constexpr int CPT = CIN / TPN;
    constexpr int SLICE = COUT + 4;          // t-rows land on disjoint banks
    constexpr int NPW = 128 / TPN;           // nodes per wave per chunk (R=2)
    constexpr int CPG = (BSg + NPW - 1) / NPW;
    constexpr int WPG = (CPG + 1) / 2;
    constexpr int NH = (COUT > 16) ? 2 : 1;
    constexpr int OH = COUT / NH;            // output-half width
    constexpr int CWH = OH / TPN;
    __shared__ float Ws[8 * CIN * SLICE];
    __shared__ float ssum[COUT], ssq[COUT];
    int tid = threadIdx.x;
    for (int idx = tid; idx < 8 * CIN * COUT; idx += 128) {
        int s = idx / (CIN * COUT), r = idx % (CIN * COUT);
        int ci = r / COUT, co = r % COUT;
        int t_ = ci / CPT, i_ = ci % CPT;
        Ws[((s * CPT + i_) * TPN + t_) * SLICE + co] = W[idx];
    }
    if (tid < COUT) { ssum[tid] = 0.f; ssq[tid] = 0.f; }
    __syncthreads();

    int w = blockIdx.x * 2 + (tid >> 6);
    int lane = tid & 63;
    int t = lane & (TPN - 1);
    int qi = lane / TPN;
    bool wact = (w < nwaves);
    int g = wact ? (w / WPG) : 0;
    int p = wact ? (w % WPG) : 0;

    float sc[CPT], sh[CPT];
    if constexpr (BN) {
#pragma unroll
        for (int i = 0; i < CPT; i++) {
            int c = t * CPT + i;
            float mean = st[c] * invcnt;
            float var = st[CIN + c] * invcnt - mean * mean;
            float s = rsqrtf(var + EPSbn) * gam[c];
            sc[i] = s; sh[i] = bet[c] - mean * s;
        }
    }

    for (int rep = 0; rep < 2; rep++) {
        if (!wact) break;
        int c = rep ? (CPG - 1 - p) : p;
        if (rep && c == p) break;              // odd CPG middle chunk: do once
        int base = g * BSg + c * NPW;
        int lim = min(NPW, BSg - c * NPW);
        int no = 2 * qi;
        bool act = no < lim;
        int n0 = base + no;

        float agg[2][8 * CPT];
#pragma unroll
        for (int r = 0; r < 2; r++)
#pragma unroll
            for (int i = 0; i < 8 * CPT; i++) agg[r][i] = 0.f;

        int dg0 = 0, dg1 = 0, jb0 = 0, jb1 = 0;
        if (act) {
            jb0 = off[n0];     dg0 = deg[n0];
            jb1 = off[n0 + 1]; dg1 = deg[n0 + 1];
        }
        int mx = max(dg0, dg1);
        int cl0 = max(dg0 - 1, 0), cl1 = max(dg1 - 1, 0);
        float4 rec0 = erec[min(jb0, NE - 1)];
        float4 rec1 = erec[min(jb1, NE - 1)];
        for (int m = 0; m < mx; m++) {
            int s0 = __float_as_int(rec0.x);
            int s1 = __float_as_int(rec1.x);
            const float* xs0 = &x[(size_t)s0 * CIN + t * CPT];
            const float* xs1 = &x[(size_t)s1 * CIN + t * CPT];
            float xv0[CPT], xv1[CPT];
            if constexpr (CPT == 4) {
                float4 v0 = *(const float4*)xs0;
                float4 v1 = *(const float4*)xs1;
                xv0[0] = v0.x; xv0[1] = v0.y; xv0[2] = v0.z; xv0[3] = v0.w;
                xv1[0] = v1.x; xv1[1] = v1.y; xv1[2] = v1.z; xv1[3] = v1.w;
            } else if constexpr (CPT == 8) {
#pragma unroll
                for (int i = 0; i < 8; i += 4) {
                    float4 v0 = *(const float4*)&xs0[i];
                    float4 v1 = *(const float4*)&xs1[i];
                    xv0[i] = v0.x; xv0[i + 1] = v0.y; xv0[i + 2] = v0.z; xv0[i + 3] = v0.w;
                    xv1[i] = v1.x; xv1[i + 1] = v1.y; xv1[i + 2] = v1.z; xv1[i + 3] = v1.w;
                }
            } else {
#pragma unroll
                for (int i = 0; i < CPT; i++) { xv0[i] = xs0[i]; xv1[i] = xs1[i]; }
            }
            float4 nrec0 = erec[jb0 + min(m + 1, cl0)];
            float4 nrec1 = erec[jb1 + min(m + 1, cl1)];
            float f0 = (m < dg0) ? 1.f : 0.f;
            float f1 = (m < dg1) ? 1.f : 0.f;
            if constexpr (BN) {
#pragma unroll
                for (int i = 0; i < CPT; i++) {
                    float a = xv0[i] * sc[i] + sh[i]; xv0[i] = a > 0.f ? a : 0.f;
                    float b = xv1[i] * sc[i] + sh[i]; xv1[i] = b > 0.f ? b : 0.f;
                }
            }
            {
                float p0 = rec0.y, p1 = rec0.z;
                float p2 = rec0.w * f0, q2 = (1.f - rec0.w) * f0;
                float q0 = 1.f - p0, q1 = 1.f - p1;
                float a00 = q0 * q1, a10 = p0 * q1, a01 = q0 * p1, a11 = p0 * p1;
                float bbv[8] = {a00 * q2, a10 * q2, a01 * q2, a11 * q2,
                                a00 * p2, a10 * p2, a01 * p2, a11 * p2};
#pragma unroll
                for (int k = 0; k < 8; k++)
#pragma unroll
                    for (int i = 0; i < CPT; i++) agg[0][k * CPT + i] += bbv[k] * xv0[i];
            }
            {
                float p0 = rec1.y, p1 = rec1.z;
                float p2 = rec1.w * f1, q2 = (1.f - rec1.w) * f1;
                float q0 = 1.f - p0, q1 = 1.f - p1;
                float a00 = q0 * q1, a10 = p0 * q1, a01 = q0 * p1, a11 = p0 * p1;
                float bbv[8] = {a00 * q2, a10 * q2, a01 * q2, a11 * q2,
                                a00 * p2, a10 * p2, a01 * p2, a11 * p2};
#pragma unroll
                for (int k = 0; k < 8; k++)
#pragma unroll
                    for (int i = 0; i < CPT; i++) agg[1][k * CPT + i] += bbv[k] * xv1[i];
            }
            rec0 = nrec0; rec1 = nrec1;
        }

        float inv0 = 1.f / (float)max(dg0, 1);
        float inv1 = 1.f / (float)max(dg1, 1);

#pragma unroll
        for (int h = 0; h < NH; h++) {
            float o0[OH], o1[OH];
#pragma unroll
            for (int c2 = 0; c2 < OH; c2++) { o0[c2] = 0.f; o1[c2] = 0.f; }
#pragma unroll
            for (int k = 0; k < 8; k++)
#pragma unroll
                for (int i = 0; i < CPT; i++) {
                    float a0 = agg[0][k * CPT + i];
                    float a1 = agg[1][k * CPT + i];
                    const float4* wr = (const float4*)&Ws[((k * CPT + i) * TPN + t) * SLICE + h * OH];
#pragma unroll
                    for (int c2 = 0; c2 < OH / 4; c2++) {
                        float4 wv = wr[c2];
                        o0[4 * c2 + 0] += a0 * wv.x; o0[4 * c2 + 1] += a0 * wv.y;
                        o0[4 * c2 + 2] += a0 * wv.z; o0[4 * c2 + 3] += a0 * wv.w;
                        o1[4 * c2 + 0] += a1 * wv.x; o1[4 * c2 + 1] += a1 * wv.y;
                        o1[4 * c2 + 2] += a1 * wv.z; o1[4 * c2 + 3] += a1 * wv.w;
                    }
                }
#pragma unroll
            for (int m = 1; m < TPN; m <<= 1)
#pragma unroll
                for (int c2 = 0; c2 < OH; c2++) { o0[c2] += __shfl_xor(o0[c2], m); o1[c2] += __shfl_xor(o1[c2], m); }

            float v0[CWH], v1[CWH], sv[CWH], qv[CWH];
#pragma unroll
            for (int c2 = 0; c2 < CWH; c2++) {
                v0[c2] = act ? o0[t * CWH + c2] * inv0 : 0.f;
                v1[c2] = act ? o1[t * CWH + c2] * inv1 : 0.f;
                sv[c2] = v0[c2] + v1[c2];
                qv[c2] = v0[c2] * v0[c2] + v1[c2] * v1[c2];
            }
            if (act) {
                float* op0 = &out[(size_t)n0 * COUT + h * OH + t * CWH];
                float* op1 = op0 + COUT;
#pragma unroll
                for (int c2 = 0; c2 < CWH; c2++) { op0[c2] = v0[c2]; op1[c2] = v1[c2]; }
            }
#pragma unroll
            for (int m = TPN; m < 64; m <<= 1)
#pragma unroll
                for (int c2 = 0; c2 < CWH; c2++) { sv[c2] += __shfl_xor(sv[c2], m); qv[c2] += __shfl_xor(qv[c2], m); }
            if (lane < TPN) {
#pragma unroll
                for (int c2 = 0; c2 < CWH; c2++) {
                    atomicAdd(&ssum[h * OH + t * CWH + c2], sv[c2]);
                    atomicAdd(&ssq[h * OH + t * CWH + c2], qv[c2]);
                }
            }
        }
    }
    __syncthreads();
    if (tid < COUT) atomicAdd(&stG[tid], ssum[tid]);
    else if (tid < 2 * COUT) atomicAdd(&stG[tid], ssq[tid - COUT]);
}

// ---------------- voxel max pool (permuted space, BN5+ReLU inline) ----------------
__global__ __launch_bounds__(256) void k_pool(const float* __restrict__ x, const int* __restrict__ cluster_p,
                                              const float* __restrict__ st, const float* __restrict__ gam,
                                              const float* __restrict__ bet, float invcnt,
                                              float* __restrict__ xp) {
    __shared__ float cellv[NCc * 32];
    __shared__ float scs[32], shs[32];
    int tid = threadIdx.x;
    int g = blockIdx.x >> 3, part = blockIdx.x & 7;
    for (int i = tid; i < NCc * 32; i += 256) cellv[i] = 0.f;
    if (tid < 32) {
        float mean = st[tid] * invcnt;
        float var = st[32 + tid] * invcnt - mean * mean;
        float s = rsqrtf(var + EPSbn) * gam[tid];
        scs[tid] = s; shs[tid] = bet[tid] - mean * s;
    }
    __syncthreads();
    int base = g * BSg + part * (BSg / 8);
    const int nelem = (BSg / 8) * 32;
    for (int ii = tid; ii < nelem; ii += 256) {
        int nd = base + (ii >> 5), ch = ii & 31;
        float v = x[(size_t)nd * 32 + ch] * scs[ch] + shs[ch];
        v = v > 0.f ? v : 0.f;
        int lc = cluster_p[nd] - g * NCc;
        atomicMax((int*)&cellv[lc * 32 + ch], __float_as_int(v));
    }
    __syncthreads();
    for (int ii = tid; ii < NCc * 32; ii += 256)
        atomicMax((int*)&xp[g * NCc * 32 + ii], __float_as_int(cellv[ii]));
}

// ---------------- pooled convs ----------------
__global__ __launch_bounds__(256) void k_y(const float* __restrict__ xp, const float* __restrict__ W,
                                           float* __restrict__ y) {
    int i = blockIdx.x * 256 + threadIdx.x;
    if (i >= MM * 256) return;
    int r = i >> 8, rem = i & 255, s = rem >> 5, co = rem & 31;
    const float* xr = &xp[r * 32];
    const float* w = &W[s * 1024 + co];
    float a = 0.f;
#pragma unroll
    for (int ci = 0; ci < 32; ci++) a += xr[ci] * w[ci * 32];
    y[i] = a;
}

// k_y2: BN+ReLU+mask applied on load.
__global__ __launch_bounds__(256) void k_y2(const float* __restrict__ pt, const float* __restrict__ W,
                                            const float* __restrict__ st, const float* __restrict__ gam,
                                            const float* __restrict__ bet, const int* __restrict__ nmask,
                                            const int* __restrict__ nmc, float* __restrict__ y) {
    __shared__ float scs[32], shs[32];
    int tid = threadIdx.x;
    if (tid < 32) {
        float cntf = (float)max(nmc[0], 1);
        float mean = st[tid] / cntf;
        float var = st[32 + tid] / cntf - mean * mean;
        float s = rsqrtf(var + EPSbn) * gam[tid];
        scs[tid] = s; shs[tid] = bet[tid] - mean * s;
    }
    __syncthreads();
    int i = blockIdx.x * 256 + tid;
    if (i >= MM * 256) return;
    int r = i >> 8, rem = i & 255, s = rem >> 5, co = rem & 31;
    float a = 0.f;
    if (nmask[r]) {
        const float* xr = &pt[r * 32];
        const float* w = &W[s * 1024 + co];
#pragma unroll
        for (int ci = 0; ci < 32; ci++) {
            float v = xr[ci] * scs[ci] + shs[ci];
            v = v > 0.f ? v : 0.f;
            a += v * w[ci * 32];
        }
    }
    y[i] = a;
}

// k_convp with fused output stats (sum/sumsq per channel -> stG).
__global__ __launch_bounds__(256) void k_convp(const float* __restrict__ y, const float* __restrict__ pp,
                                               const unsigned char* __restrict__ presence,
                                               const float* __restrict__ maxv, float* __restrict__ out,
                                               float* __restrict__ stG) {
    __shared__ float ssum[32], ssq[32];
    int tid = threadIdx.x;
    if (tid < 32) { ssum[tid] = 0.f; ssq[tid] = 0.f; }
    __syncthreads();
    int i = blockIdx.x * 256 + tid;       // grid is exactly MM*32 = 225 blocks
    int c = i >> 5, co = i & 31;
    int g = c / NCc, lc = c % NCc;
    float mv = fmaxf(maxv[0], 1e-9f);
    float inv2 = 0.5f / mv;
    float pcx = pp[c * 3], pcy = pp[c * 3 + 1], pcz = pp[c * 3 + 2];
    const unsigned char* pr = &presence[g * (NCc * NCc) + lc];
    float acc = 0.f; int dg = 0;
    for (int lr = 0; lr < NCc; lr++) {
        if (pr[lr * NCc]) {
            dg++;
            int r = g * NCc + lr;
            float p0 = fminf(fmaxf((pcx - pp[r * 3]) * inv2 + 0.5f, 0.f), 1.f);
            float p1 = fminf(fmaxf((pcy - pp[r * 3 + 1]) * inv2 + 0.5f, 0.f), 1.f);
            float p2 = fminf(fmaxf((pcz - pp[r * 3 + 2]) * inv2 + 0.5f, 0.f), 1.f);
            float q0 = 1.f - p0, q1 = 1.f - p1, q2 = 1.f - p2;
            const float* yr = &y[r * 256 + co];
            acc += (q0 * q1 * q2) * yr[0]   + (p0 * q1 * q2) * yr[32]
                 + (q0 * p1 * q2) * yr[64]  + (p0 * p1 * q2) * yr[96]
                 + (q0 * q1 * p2) * yr[128] + (p0 * q1 * p2) * yr[160]
                 + (q0 * p1 * p2) * yr[192] + (p0 * p1 * p2) * yr[224];
        }
    }
    float val = acc / (float)max(dg, 1);
    out[i] = val;
    float sv = val, qv = val * val;
    sv += __shfl_xor(sv, 32); qv += __shfl_xor(qv, 32);
    int lane = tid & 63;
    if (lane < 32) { atomicAdd(&ssum[lane], sv); atomicAdd(&ssq[lane], qv); }
    __syncthreads();
    if (tid < 32) atomicAdd(&stG[tid], ssum[tid]);
    else if (tid < 64) atomicAdd(&stG[32 + tid - 32], ssq[tid - 32]);
}

// k_poolX: BN+ReLU+mask applied on load.
__global__ __launch_bounds__(256) void k_poolX(const float* __restrict__ pt, const float* __restrict__ pp,
                                               const float* __restrict__ st, const float* __restrict__ gam,
                                               const float* __restrict__ bet, const int* __restrict__ nmask,
                                               const int* __restrict__ nmc, float* __restrict__ xg) {
    int i = blockIdx.x * 256 + threadIdx.x;
    if (i >= MM * 32) return;
    int m = i >> 5, ch = i & 31;
    if (!nmask[m]) return;
    float cntf = (float)max(nmc[0], 1);
    float mean = st[ch] / cntf;
    float var = st[32 + ch] / cntf - mean * mean;
    float s = rsqrtf(var + EPSbn) * gam[ch];
    float v = pt[i] * s + (bet[ch] - mean * s);
    v = v > 0.f ? v : 0.f;
    int g = m / NCc;
    int gx = min(max((int)floorf(pp[m * 3] / 30.f), 0), 3);
    int gy = min(max((int)floorf(pp[m * 3 + 1] / 25.f), 0), 3);
    int seg = g * 16 + gy * 4 + gx;
    atomicMax((int*)&xg[seg * 32 + ch], __float_as_int(v));
}

__global__ __launch_bounds__(64) void k_fc(const float* __restrict__ xg, const float* __restrict__ fcw,
                                           float* __restrict__ out) {
    int q = blockIdx.x;          // 50 blocks: (b, o)
    int b = q >> 1, o = q & 1;
    int l = threadIdx.x;
    float a = 0.f;
    for (int k = l; k < 512; k += 64) a += xg[b * 512 + k] * fcw[o * 512 + k];
    for (int s = 32; s; s >>= 1) a += __shfl_xor(a, s);
    if (l == 0) out[b * 2 + o] = a;
}

// ---------------- launcher ----------------

extern "C" void kernel_launch(void* const* d_in, const int* in_sizes, int n_in,
                              void* d_out, int out_size, void* d_ws, size_t ws_size,
                              hipStream_t stream) {
    const float* x_in  = (const float*)d_in[0];
    const float* pos   = (const float*)d_in[1];
    const float* eattr = (const float*)d_in[2];
    const float* w[7];  for (int i = 0; i < 7; i++) w[i]  = (const float*)d_in[3 + i];
    const float* gm[7]; for (int i = 0; i < 7; i++) gm[i] = (const float*)d_in[10 + i];
    const float* bt[7]; for (int i = 0; i < 7; i++) bt[i] = (const float*)d_in[17 + i];
    const float* fcw   = (const float*)d_in[24];
    const int* ei      = (const int*)d_in[25];
    const int* batch   = (const int*)d_in[26];
    const int* esrc = ei;
    const int* edst = ei + NE;
    float* outp = (float*)d_out;

    char* base = (char*)d_ws;
    size_t cur = 0;
    auto alloc = [&](size_t elems) -> void* {
        void* p = base + cur;
        cur += (((elems * 4) + 255) & ~(size_t)255);
        return p;
    };
    // ---- zero-initialized region ----
    int*   deg_i     = (int*)alloc(NN);
    int*   cursor    = (int*)alloc(NN);
    int*   cnt_i     = (int*)alloc(MM);
    float* ppsum     = (float*)alloc(MM * 3);
    unsigned char* presence = (unsigned char*)alloc(PRES / 4);
    float* maxv      = (float*)alloc(64);
    int*   nmc       = (int*)alloc(64);
    int*   dhist     = (int*)alloc(NBK);
    float* st        = (float*)alloc(7 * 64);   // 7 slots: [sum C | sumsq C]
    float* xp_pool   = (float*)alloc(MM * 32);
    float* xg        = (float*)alloc(NBm * 16 * 32);
    size_t zero_bytes = cur;
    // ---- uninitialized region ----
    int*   off_ex    = (int*)alloc(NN);
    int*   bsum      = (int*)alloc(256);
    int*   cluster   = (int*)alloc(NN);
    int*   cluster_p = (int*)alloc(NN);
    int*   dcur      = (int*)alloc(NBK);
    int*   pinv      = (int*)alloc(NN);
    int*   deg_p     = (int*)alloc(NN);
    float* xin_p     = (float*)alloc(NN);
    float4* erec     = (float4*)alloc((size_t)NE * 4);
    float* x_a       = (float*)alloc((size_t)NN * 32);
    float* x_b       = (float*)alloc((size_t)NN * 16);
    float* pp        = (float*)alloc(MM * 3);
    int*   nmask     = (int*)alloc(MM);
    float* ybuf      = (float*)alloc(MM * 256);
    float* pt0       = (float*)alloc(MM * 32);
    float* pt1       = (float*)alloc(MM * 32);
    (void)ws_size; (void)in_sizes; (void)n_in; (void)out_size;

    (void)hipMemsetAsync(d_ws, 0, zero_bytes, stream);

    int gE = (NE + 255) / 256;
    int gN = (NN + 255) / 256;
    int nbS = (NN + 2047) / 2048;

    k_deg<<<gE, 256, 0, stream>>>(edst, deg_i, NE);
    k_dhist<<<gN, 256, 0, stream>>>(deg_i, batch, dhist, NN);
    k_dscan<<<1, 256, 0, stream>>>(dhist, dcur);
    k_dscat<<<gN, 256, 0, stream>>>(deg_i, batch, x_in, dcur, pinv, deg_p, xin_p, NN);
    k_scan1<<<nbS, 256, 0, stream>>>(deg_p, NN, off_ex, bsum);
    k_scan2<<<1, 256, 0, stream>>>(bsum, nbS);
    k_scan3<<<gN, 256, 0, stream>>>(off_ex, NN, bsum);
    k_cluster<<<NBm * 8, 256, 0, stream>>>(pos, pinv, cluster, cluster_p, cnt_i, ppsum);
    k_scatter<<<gE, 256, 0, stream>>>(esrc, edst, eattr, off_ex, pinv, cluster, cursor, erec, presence, NE);
    k_fpp<<<(MM + 255) / 256, 256, 0, stream>>>(cnt_i, ppsum, pp, nmask, nmc);
    k_maxv<<<(PRES + 255) / 256, 256, 0, stream>>>(presence, pp, maxv);

    const float invN = 1.f / (float)NN;
    // mirror-paired wave counts, 2 waves/block:
    constexpr int W1 = NBm * ((((BSg + 127) / 128) + 1) / 2);   // TPN=1 -> 1000
    constexpr int W2 = NBm * ((((BSg + 63) / 64) + 1) / 2);     // TPN=2 -> 1975
    constexpr int W4 = NBm * ((((BSg + 31) / 32) + 1) / 2);     // TPN=4 -> 3925
    // conv1: 1 -> 8
    k_conv<1, 8, 1, false><<<(W1 + 1) / 2, 128, 0, stream>>>(xin_p, erec, off_ex, deg_p,
                                                             w[0], nullptr, nullptr, nullptr, 0.f, x_a, st + 0, W1);
    // conv2: 8 -> 16 (BN1+ReLU inline on gather)
    k_conv<8, 16, 2, true><<<(W2 + 1) / 2, 128, 0, stream>>>(x_a, erec, off_ex, deg_p,
                                                             w[1], st + 0, gm[0], bt[0], invN, x_b, st + 64, W2);
    // conv3: 16 -> 16
    k_conv<16, 16, 4, true><<<(W4 + 1) / 2, 128, 0, stream>>>(x_b, erec, off_ex, deg_p,
                                                              w[2], st + 64, gm[1], bt[1], invN, x_a, st + 128, W4);
    // conv4: 16 -> 16
    k_conv<16, 16, 4, true><<<(W4 + 1) / 2, 128, 0, stream>>>(x_a, erec, off_ex, deg_p,
                                                              w[3], st + 128, gm[2], bt[2], invN, x_b, st + 192, W4);
    // conv5: 16 -> 32
    k_conv<16, 32, 4, true><<<(W4 + 1) / 2, 128, 0, stream>>>(x_b, erec, off_ex, deg_p,
                                                              w[4], st + 192, gm[3], bt[3], invN, x_a, st + 256, W4);
    // voxel max pool (BN5+ReLU inline), LDS-staged, permuted space
    k_pool<<<NBm * 8, 256, 0, stream>>>(x_a, cluster_p, st + 256, gm[4], bt[4], invN, xp_pool);
    // conv6 on pooled graph (stats fused into k_convp)
    k_y<<<(MM * 256 + 255) / 256, 256, 0, stream>>>(xp_pool, w[5], ybuf);
    k_convp<<<(MM * 32) / 256, 256, 0, stream>>>(ybuf, pp, presence, maxv, pt0, st + 320);
    // conv7 (BN6+ReLU+mask applied on k_y2 load; stats fused into k_convp)
    k_y2<<<(MM * 256 + 255) / 256, 256, 0, stream>>>(pt0, w[6], st + 320, gm[5], bt[5], nmask, nmc, ybuf);
    k_convp<<<(MM * 32) / 256, 256, 0, stream>>>(ybuf, pp, presence, maxv, pt1, st + 384);
    // MaxPoolingX (BN7+ReLU+mask on load) + FC
    k_poolX<<<(MM * 32 + 255) / 256, 256, 0, stream>>>(pt1, pp, st + 384, gm[6], bt[6], nmask, nmc, xg);
    k_fc<<<50, 64, 0, stream>>>(xg, fcw, outp);
}

// Round 16
// 622.520 us; speedup vs baseline: 1.0794x; 1.0794x over previous
//
#include <hip/hip_runtime.h>

constexpr int NN   = 250000;      // nodes
constexpr int NE   = 1000000;     // edges
constexpr int NBm  = 25;          // graphs
constexpr int BSg  = NN / NBm;    // 10000 nodes per graph
constexpr int NCc  = 72;          // voxel cells per graph
constexpr int MM   = NBm * NCc;   // 1800 pooled slots
constexpr int PRES = NBm * NCc * NCc; // 129600 coarse-edge presence slots
constexpr int NBK  = NBm * 16;    // 400 sort buckets: graph*16 + (15 - min(deg,15))  [descending]
constexpr float EPSbn = 1e-5f;

// ---------------- graph prep ----------------

__global__ __launch_bounds__(256) void k_deg(const int* __restrict__ dst, int* __restrict__ deg, int n) {
    int e = blockIdx.x * 256 + threadIdx.x;
    if (e < n) atomicAdd(&deg[dst[e]], 1);
}

// per-block LDS histogram over 400 (graph,deg) buckets -> low-contention global adds
__global__ __launch_bounds__(256) void k_dhist(const int* __restrict__ deg, const int* __restrict__ batch,
                                               int* __restrict__ dhist, int n) {
    __shared__ int h[NBK];
    int tid = threadIdx.x;
    for (int i = tid; i < NBK; i += 256) h[i] = 0;
    __syncthreads();
    int i = blockIdx.x * 256 + tid;
    if (i < n) atomicAdd(&h[batch[i] * 16 + (15 - min(deg[i], 15))], 1);
    __syncthreads();
    for (int b = tid; b < NBK; b += 256) if (h[b]) atomicAdd(&dhist[b], h[b]);
}

__global__ __launch_bounds__(256) void k_dscan(const int* __restrict__ dhist, int* __restrict__ dcur) {
    __shared__ int tmp[NBK];
    int t = threadIdx.x;
    for (int i = t; i < NBK; i += 256) tmp[i] = dhist[i];
    __syncthreads();
    if (t == 0) { int run = 0; for (int i = 0; i < NBK; i++) { int v = tmp[i]; tmp[i] = run; run += v; } }
    __syncthreads();
    for (int i = t; i < NBK; i += 256) dcur[i] = tmp[i];
}

// two-phase scatter: LDS local ranks + one ranged global atomicAdd per (block,bucket).
__global__ __launch_bounds__(256) void k_dscat(const int* __restrict__ deg, const int* __restrict__ batch,
                                               const float* __restrict__ x_in,
                                               int* __restrict__ dcur, int* __restrict__ pinv,
                                               int* __restrict__ deg_p, float* __restrict__ xin_p, int n) {
    __shared__ int lcnt[NBK];
    __shared__ int gbase[NBK];
    int tid = threadIdx.x;
    for (int i = tid; i < NBK; i += 256) lcnt[i] = 0;
    __syncthreads();
    int i = blockIdx.x * 256 + tid;
    int b = 0, rank = 0;
    if (i < n) {
        b = batch[i] * 16 + (15 - min(deg[i], 15));
        rank = atomicAdd(&lcnt[b], 1);
    }
    __syncthreads();
    for (int k = tid; k < NBK; k += 256)
        if (lcnt[k]) gbase[k] = atomicAdd(&dcur[k], lcnt[k]);
    __syncthreads();
    if (i < n) {
        int slot = gbase[b] + rank;
        pinv[i] = slot;
        deg_p[slot] = deg[i];
        xin_p[slot] = x_in[i];
    }
}

__global__ __launch_bounds__(256) void k_scan1(const int* __restrict__ in, int n,
                                               int* __restrict__ outEx, int* __restrict__ bsum) {
    __shared__ int lds[256];
    int t = threadIdx.x;
    int base = blockIdx.x * 2048;
    int v[8]; int s = 0;
#pragma unroll
    for (int i = 0; i < 8; i++) { int idx = base + t * 8 + i; v[i] = (idx < n) ? in[idx] : 0; s += v[i]; }
    lds[t] = s; __syncthreads();
    for (int o = 1; o < 256; o <<= 1) {
        int x = (t >= o) ? lds[t - o] : 0; __syncthreads();
        lds[t] += x; __syncthreads();
    }
    if (t == 255) bsum[blockIdx.x] = lds[255];
    int run = lds[t] - s;
#pragma unroll
    for (int i = 0; i < 8; i++) { int idx = base + t * 8 + i; if (idx < n) outEx[idx] = run; run += v[i]; }
}

__global__ __launch_bounds__(256) void k_scan2(int* bsum, int nb) {
    __shared__ int l[256];
    int t = threadIdx.x;
    int v = (t < nb) ? bsum[t] : 0;
    l[t] = v; __syncthreads();
    for (int o = 1; o < 256; o <<= 1) {
        int x = (t >= o) ? l[t - o] : 0; __syncthreads();
        l[t] += x; __syncthreads();
    }
    if (t < nb) bsum[t] = l[t] - v;   // exclusive
}

__global__ __launch_bounds__(256) void k_scan3(int* __restrict__ outEx, int n, const int* __restrict__ bsum) {
    int i = blockIdx.x * 256 + threadIdx.x;
    if (i < n) outEx[i] += bsum[i >> 11];
}

// LDS-staged cluster assignment + per-cell count/pos sums (R13: 75us -> ~8us).
__global__ __launch_bounds__(256) void k_cluster(const float* __restrict__ pos, const int* __restrict__ pinv,
                                                 int* __restrict__ cluster, int* __restrict__ cluster_p,
                                                 int* __restrict__ cnt, float* __restrict__ ppsum) {
    __shared__ int lcnt[NCc];
    __shared__ float lpp[NCc * 3];
    int tid = threadIdx.x;
    int g = blockIdx.x >> 3, part = blockIdx.x & 7;
    for (int i = tid; i < NCc; i += 256) lcnt[i] = 0;
    for (int i = tid; i < NCc * 3; i += 256) lpp[i] = 0.f;
    __syncthreads();
    int base = g * BSg + part * (BSg / 8);
    int lim = BSg / 8;
    for (int k = tid; k < lim; k += 256) {
        int i = base + k;
        float px = pos[i * 3], py = pos[i * 3 + 1], pz = pos[i * 3 + 2];
        int cx = min(max((int)floorf(px / 16.f), 0), 7);
        int cy = min(max((int)floorf(py / 12.f), 0), 8);
        int lc = cy * 8 + cx;
        cluster[i] = g * NCc + lc;
        cluster_p[pinv[i]] = g * NCc + lc;
        atomicAdd(&lcnt[lc], 1);
        atomicAdd(&lpp[lc * 3 + 0], px);
        atomicAdd(&lpp[lc * 3 + 1], py);
        atomicAdd(&lpp[lc * 3 + 2], pz);
    }
    __syncthreads();
    for (int c = tid; c < NCc; c += 256) {
        if (lcnt[c]) {
            atomicAdd(&cnt[g * NCc + c], lcnt[c]);
            atomicAdd(&ppsum[(g * NCc + c) * 3 + 0], lpp[c * 3 + 0]);
            atomicAdd(&ppsum[(g * NCc + c) * 3 + 1], lpp[c * 3 + 1]);
            atomicAdd(&ppsum[(g * NCc + c) * 3 + 2], lpp[c * 3 + 2]);
        }
    }
}

// Fused: edge record scatter (CSR by permuted dst) + coarse-edge presence map.
__global__ __launch_bounds__(256) void k_scatter(const int* __restrict__ src, const int* __restrict__ dst,
                                                 const float* __restrict__ ea, const int* __restrict__ offx,
                                                 const int* __restrict__ pinv, const int* __restrict__ cluster,
                                                 int* __restrict__ cursor, float4* __restrict__ erec,
                                                 unsigned char* __restrict__ presence, int n) {
    int e = blockIdx.x * 256 + threadIdx.x;
    if (e >= n) return;
    int s = src[e], d = dst[e];
    int pd = pinv[d];
    int j = offx[pd] + atomicAdd(&cursor[pd], 1);
    float p0 = fminf(fmaxf(ea[e * 3 + 0], 0.f), 1.f);
    float p1 = fminf(fmaxf(ea[e * 3 + 1], 0.f), 1.f);
    float p2 = fminf(fmaxf(ea[e * 3 + 2], 0.f), 1.f);
    erec[j] = make_float4(__int_as_float(pinv[s]), p0, p1, p2);
    int r = cluster[s], c = cluster[d];
    if (r != c) {
        int g = r / NCc;
        presence[g * (NCc * NCc) + (r % NCc) * NCc + (c % NCc)] = 1;
    }
}

__global__ __launch_bounds__(256) void k_fpp(const int* __restrict__ cnt, const float* __restrict__ ppsum,
                                             float* __restrict__ pp, int* __restrict__ nmask, int* __restrict__ nmc) {
    int m = blockIdx.x * 256 + threadIdx.x;
    if (m >= MM) return;
    int c = cnt[m];
    float inv = 1.f / (float)max(c, 1);
    pp[m * 3 + 0] = ppsum[m * 3 + 0] * inv;
    pp[m * 3 + 1] = ppsum[m * 3 + 1] * inv;
    pp[m * 3 + 2] = ppsum[m * 3 + 2] * inv;
    nmask[m] = (c > 0);
    if (c > 0) atomicAdd(nmc, 1);
}

__global__ __launch_bounds__(256) void k_maxv(const unsigned char* __restrict__ presence, const float* __restrict__ pp,
                                              float* __restrict__ maxv) {
    int i = blockIdx.x * 256 + threadIdx.x;
    float m = 0.f;
    if (i < PRES && presence[i]) {
        int g = i / (NCc * NCc), rem = i % (NCc * NCc);
        int r = g * NCc + rem / NCc, c = g * NCc + rem % NCc;
        float d0 = fabsf(pp[c * 3 + 0] - pp[r * 3 + 0]);
        float d1 = fabsf(pp[c * 3 + 1] - pp[r * 3 + 1]);
        float d2 = fabsf(pp[c * 3 + 2] - pp[r * 3 + 2]);
        m = fmaxf(fmaxf(d0, d1), d2);
    }
    for (int o = 32; o; o >>= 1) m = fmaxf(m, __shfl_xor(m, o));
    if ((threadIdx.x & 63) == 0) atomicMax((int*)maxv, __float_as_int(m));
}

// ---------------- full-graph spline conv ----------------
// R12/R13 exact configuration (measured best: 74.0us for conv5):
// mirror-paired balanced waves (R=2), 256-thread blocks, depth-1 pipelined
// branchless edge loop.

template <int CIN, int COUT, int TPN, bool BN>
__global__ __launch_bounds__(256) void k_conv(
    const float* __restrict__ x, const float4* __restrict__ erec,
    const int* __restrict__ off, const int* __restrict__ deg,
    const float* __restrict__ W, const float* __restrict__ st,
    const float* __restrict__ gam, const float* __restrict__ bet, float invcnt,
    float* __restrict__ out, float* __restrict__ stG, int nwaves) {
    constexpr int CPT = CIN / TPN;
    constexpr int SLICE = COUT + 4;          // t-rows land on disjoint banks
    constexpr int NPW = 128 / TPN;           // nodes per wave per chunk (R=2)
    constexpr int CPG = (BSg + NPW - 1) / NPW;
    constexpr int WPG = (CPG + 1) / 2;
    constexpr int NH = (COUT > 16) ? 2 : 1;
    constexpr int OH = COUT / NH;            // output-half width
    constexpr int CWH = OH / TPN;
    __shared__ float Ws[8 * CIN * SLICE];
    __shared__ float ssum[COUT], ssq[COUT];
    int tid = threadIdx.x;
    for (int idx = tid; idx < 8 * CIN * COUT; idx += 256) {
        int s = idx / (CIN * COUT), r = idx % (CIN * COUT);
        int ci = r / COUT, co = r % COUT;
        int t_ = ci / CPT, i_ = ci % CPT;
        Ws[((s * CPT + i_) * TPN + t_) * SLICE + co] = W[idx];
    }
    if (tid < COUT) { ssum[tid] = 0.f; ssq[tid] = 0.f; }
    __syncthreads();

    int w = blockIdx.x * 4 + (tid >> 6);
    int lane = tid & 63;
    int t = lane & (TPN - 1);
    int qi = lane / TPN;
    bool wact = (w < nwaves);
    int g = wact ? (w / WPG) : 0;
    int p = wact ? (w % WPG) : 0;

    float sc[CPT], sh[CPT];
    if constexpr (BN) {
#pragma unroll
        for (int i = 0; i < CPT; i++) {
            int c = t * CPT + i;
            float mean = st[c] * invcnt;
            float var = st[CIN + c] * invcnt - mean * mean;
            float s = rsqrtf(var + EPSbn) * gam[c];
            sc[i] = s; sh[i] = bet[c] - mean * s;
        }
    }

    for (int rep = 0; rep < 2; rep++) {
        if (!wact) break;
        int c = rep ? (CPG - 1 - p) : p;
        if (rep && c == p) break;              // odd CPG middle chunk: do once
        int base = g * BSg + c * NPW;
        int lim = min(NPW, BSg - c * NPW);
        int no = 2 * qi;
        bool act = no < lim;
        int n0 = base + no;

        float agg[2][8 * CPT];
#pragma unroll
        for (int r = 0; r < 2; r++)
#pragma unroll
            for (int i = 0; i < 8 * CPT; i++) agg[r][i] = 0.f;

        int dg0 = 0, dg1 = 0, jb0 = 0, jb1 = 0;
        if (act) {
            jb0 = off[n0];     dg0 = deg[n0];
            jb1 = off[n0 + 1]; dg1 = deg[n0 + 1];
        }
        int mx = max(dg0, dg1);
        int cl0 = max(dg0 - 1, 0), cl1 = max(dg1 - 1, 0);
        float4 rec0 = erec[min(jb0, NE - 1)];
        float4 rec1 = erec[min(jb1, NE - 1)];
        for (int m = 0; m < mx; m++) {
            int s0 = __float_as_int(rec0.x);
            int s1 = __float_as_int(rec1.x);
            const float* xs0 = &x[(size_t)s0 * CIN + t * CPT];
            const float* xs1 = &x[(size_t)s1 * CIN + t * CPT];
            float xv0[CPT], xv1[CPT];
            if constexpr (CPT == 4) {
                float4 v0 = *(const float4*)xs0;
                float4 v1 = *(const float4*)xs1;
                xv0[0] = v0.x; xv0[1] = v0.y; xv0[2] = v0.z; xv0[3] = v0.w;
                xv1[0] = v1.x; xv1[1] = v1.y; xv1[2] = v1.z; xv1[3] = v1.w;
            } else if constexpr (CPT == 8) {
#pragma unroll
                for (int i = 0; i < 8; i += 4) {
                    float4 v0 = *(const float4*)&xs0[i];
                    float4 v1 = *(const float4*)&xs1[i];
                    xv0[i] = v0.x; xv0[i + 1] = v0.y; xv0[i + 2] = v0.z; xv0[i + 3] = v0.w;
                    xv1[i] = v1.x; xv1[i + 1] = v1.y; xv1[i + 2] = v1.z; xv1[i + 3] = v1.w;
                }
            } else {
#pragma unroll
                for (int i = 0; i < CPT; i++) { xv0[i] = xs0[i]; xv1[i] = xs1[i]; }
            }
            float4 nrec0 = erec[jb0 + min(m + 1, cl0)];
            float4 nrec1 = erec[jb1 + min(m + 1, cl1)];
            float f0 = (m < dg0) ? 1.f : 0.f;
            float f1 = (m < dg1) ? 1.f : 0.f;
            if constexpr (BN) {
#pragma unroll
                for (int i = 0; i < CPT; i++) {
                    float a = xv0[i] * sc[i] + sh[i]; xv0[i] = a > 0.f ? a : 0.f;
                    float b = xv1[i] * sc[i] + sh[i]; xv1[i] = b > 0.f ? b : 0.f;
                }
            }
            {
                float p0 = rec0.y, p1 = rec0.z;
                float p2 = rec0.w * f0, q2 = (1.f - rec0.w) * f0;
                float q0 = 1.f - p0, q1 = 1.f - p1;
                float a00 = q0 * q1, a10 = p0 * q1, a01 = q0 * p1, a11 = p0 * p1;
                float bbv[8] = {a00 * q2, a10 * q2, a01 * q2, a11 * q2,
                                a00 * p2, a10 * p2, a01 * p2, a11 * p2};
#pragma unroll
                for (int k = 0; k < 8; k++)
#pragma unroll
                    for (int i = 0; i < CPT; i++) agg[0][k * CPT + i] += bbv[k] * xv0[i];
            }
            {
                float p0 = rec1.y, p1 = rec1.z;
                float p2 = rec1.w * f1, q2 = (1.f - rec1.w) * f1;
                float q0 = 1.f - p0, q1 = 1.f - p1;
                float a00 = q0 * q1, a10 = p0 * q1, a01 = q0 * p1, a11 = p0 * p1;
                float bbv[8] = {a00 * q2, a10 * q2, a01 * q2, a11 * q2,
                                a00 * p2, a10 * p2, a01 * p2, a11 * p2};
#pragma unroll
                for (int k = 0; k < 8; k++)
#pragma unroll
                    for (int i = 0; i < CPT; i++) agg[1][k * CPT + i] += bbv[k] * xv1[i];
            }
            rec0 = nrec0; rec1 = nrec1;
        }

        float inv0 = 1.f / (float)max(dg0, 1);
        float inv1 = 1.f / (float)max(dg1, 1);

#pragma unroll
        for (int h = 0; h < NH; h++) {
            float o0[OH], o1[OH];
#pragma unroll
            for (int c2 = 0; c2 < OH; c2++) { o0[c2] = 0.f; o1[c2] = 0.f; }
#pragma unroll
            for (int k = 0; k < 8; k++)
#pragma unroll
                for (int i = 0; i < CPT; i++) {
                    float a0 = agg[0][k * CPT + i];
                    float a1 = agg[1][k * CPT + i];
                    const float4* wr = (const float4*)&Ws[((k * CPT + i) * TPN + t) * SLICE + h * OH];
#pragma unroll
                    for (int c2 = 0; c2 < OH / 4; c2++) {
                        float4 wv = wr[c2];
                        o0[4 * c2 + 0] += a0 * wv.x; o0[4 * c2 + 1] += a0 * wv.y;
                        o0[4 * c2 + 2] += a0 * wv.z; o0[4 * c2 + 3] += a0 * wv.w;
                        o1[4 * c2 + 0] += a1 * wv.x; o1[4 * c2 + 1] += a1 * wv.y;
                        o1[4 * c2 + 2] += a1 * wv.z; o1[4 * c2 + 3] += a1 * wv.w;
                    }
                }
#pragma unroll
            for (int m = 1; m < TPN; m <<= 1)
#pragma unroll
                for (int c2 = 0; c2 < OH; c2++) { o0[c2] += __shfl_xor(o0[c2], m); o1[c2] += __shfl_xor(o1[c2], m); }

            float v0[CWH], v1[CWH], sv[CWH], qv[CWH];
#pragma unroll
            for (int c2 = 0; c2 < CWH; c2++) {
                v0[c2] = act ? o0[t * CWH + c2] * inv0 : 0.f;
                v1[c2] = act ? o1[t * CWH + c2] * inv1 : 0.f;
                sv[c2] = v0[c2] + v1[c2];
                qv[c2] = v0[c2] * v0[c2] + v1[c2] * v1[c2];
            }
            if (act) {
                float* op0 = &out[(size_t)n0 * COUT + h * OH + t * CWH];
                float* op1 = op0 + COUT;
#pragma unroll
                for (int c2 = 0; c2 < CWH; c2++) { op0[c2] = v0[c2]; op1[c2] = v1[c2]; }
            }
#pragma unroll
            for (int m = TPN; m < 64; m <<= 1)
#pragma unroll
                for (int c2 = 0; c2 < CWH; c2++) { sv[c2] += __shfl_xor(sv[c2], m); qv[c2] += __shfl_xor(qv[c2], m); }
            if (lane < TPN) {
#pragma unroll
                for (int c2 = 0; c2 < CWH; c2++) {
                    atomicAdd(&ssum[h * OH + t * CWH + c2], sv[c2]);
                    atomicAdd(&ssq[h * OH + t * CWH + c2], qv[c2]);
                }
            }
        }
    }
    __syncthreads();
    if (tid < COUT) atomicAdd(&stG[tid], ssum[tid]);
    else if (tid < 2 * COUT) atomicAdd(&stG[tid], ssq[tid - COUT]);
}

// ---------------- voxel max pool (permuted space, BN5+ReLU inline) ----------------
__global__ __launch_bounds__(256) void k_pool(const float* __restrict__ x, const int* __restrict__ cluster_p,
                                              const float* __restrict__ st, const float* __restrict__ gam,
                                              const float* __restrict__ bet, float invcnt,
                                              float* __restrict__ xp) {
    __shared__ float cellv[NCc * 32];
    __shared__ float scs[32], shs[32];
    int tid = threadIdx.x;
    int g = blockIdx.x >> 3, part = blockIdx.x & 7;
    for (int i = tid; i < NCc * 32; i += 256) cellv[i] = 0.f;
    if (tid < 32) {
        float mean = st[tid] * invcnt;
        float var = st[32 + tid] * invcnt - mean * mean;
        float s = rsqrtf(var + EPSbn) * gam[tid];
        scs[tid] = s; shs[tid] = bet[tid] - mean * s;
    }
    __syncthreads();
    int base = g * BSg + part * (BSg / 8);
    const int nelem = (BSg / 8) * 32;
    for (int ii = tid; ii < nelem; ii += 256) {
        int nd = base + (ii >> 5), ch = ii & 31;
        float v = x[(size_t)nd * 32 + ch] * scs[ch] + shs[ch];
        v = v > 0.f ? v : 0.f;
        int lc = cluster_p[nd] - g * NCc;
        atomicMax((int*)&cellv[lc * 32 + ch], __float_as_int(v));
    }
    __syncthreads();
    for (int ii = tid; ii < NCc * 32; ii += 256)
        atomicMax((int*)&xp[g * NCc * 32 + ii], __float_as_int(cellv[ii]));
}

// ---------------- pooled convs ----------------
__global__ __launch_bounds__(256) void k_y(const float* __restrict__ xp, const float* __restrict__ W,
                                           float* __restrict__ y) {
    int i = blockIdx.x * 256 + threadIdx.x;
    if (i >= MM * 256) return;
    int r = i >> 8, rem = i & 255, s = rem >> 5, co = rem & 31;
    const float* xr = &xp[r * 32];
    const float* w = &W[s * 1024 + co];
    float a = 0.f;
#pragma unroll
    for (int ci = 0; ci < 32; ci++) a += xr[ci] * w[ci * 32];
    y[i] = a;
}

// k_y2: BN+ReLU+mask applied on load.
__global__ __launch_bounds__(256) void k_y2(const float* __restrict__ pt, const float* __restrict__ W,
                                            const float* __restrict__ st, const float* __restrict__ gam,
                                            const float* __restrict__ bet, const int* __restrict__ nmask,
                                            const int* __restrict__ nmc, float* __restrict__ y) {
    __shared__ float scs[32], shs[32];
    int tid = threadIdx.x;
    if (tid < 32) {
        float cntf = (float)max(nmc[0], 1);
        float mean = st[tid] / cntf;
        float var = st[32 + tid] / cntf - mean * mean;
        float s = rsqrtf(var + EPSbn) * gam[tid];
        scs[tid] = s; shs[tid] = bet[tid] - mean * s;
    }
    __syncthreads();
    int i = blockIdx.x * 256 + tid;
    if (i >= MM * 256) return;
    int r = i >> 8, rem = i & 255, s = rem >> 5, co = rem & 31;
    float a = 0.f;
    if (nmask[r]) {
        const float* xr = &pt[r * 32];
        const float* w = &W[s * 1024 + co];
#pragma unroll
        for (int ci = 0; ci < 32; ci++) {
            float v = xr[ci] * scs[ci] + shs[ci];
            v = v > 0.f ? v : 0.f;
            a += v * w[ci * 32];
        }
    }
    y[i] = a;
}

// k_convp with fused output stats (sum/sumsq per channel -> stG).
__global__ __launch_bounds__(256) void k_convp(const float* __restrict__ y, const float* __restrict__ pp,
                                               const unsigned char* __restrict__ presence,
                                               const float* __restrict__ maxv, float* __restrict__ out,
                                               float* __restrict__ stG) {
    __shared__ float ssum[32], ssq[32];
    int tid = threadIdx.x;
    if (tid < 32) { ssum[tid] = 0.f; ssq[tid] = 0.f; }
    __syncthreads();
    int i = blockIdx.x * 256 + tid;       // grid is exactly MM*32 = 225 blocks
    int c = i >> 5, co = i & 31;
    int g = c / NCc, lc = c % NCc;
    float mv = fmaxf(maxv[0], 1e-9f);
    float inv2 = 0.5f / mv;
    float pcx = pp[c * 3], pcy = pp[c * 3 + 1], pcz = pp[c * 3 + 2];
    const unsigned char* pr = &presence[g * (NCc * NCc) + lc];
    float acc = 0.f; int dg = 0;
    for (int lr = 0; lr < NCc; lr++) {
        if (pr[lr * NCc]) {
            dg++;
            int r = g * NCc + lr;
            float p0 = fminf(fmaxf((pcx - pp[r * 3]) * inv2 + 0.5f, 0.f), 1.f);
            float p1 = fminf(fmaxf((pcy - pp[r * 3 + 1]) * inv2 + 0.5f, 0.f), 1.f);
            float p2 = fminf(fmaxf((pcz - pp[r * 3 + 2]) * inv2 + 0.5f, 0.f), 1.f);
            float q0 = 1.f - p0, q1 = 1.f - p1, q2 = 1.f - p2;
            const float* yr = &y[r * 256 + co];
            acc += (q0 * q1 * q2) * yr[0]   + (p0 * q1 * q2) * yr[32]
                 + (q0 * p1 * q2) * yr[64]  + (p0 * p1 * q2) * yr[96]
                 + (q0 * q1 * p2) * yr[128] + (p0 * q1 * p2) * yr[160]
                 + (q0 * p1 * p2) * yr[192] + (p0 * p1 * p2) * yr[224];
        }
    }
    float val = acc / (float)max(dg, 1);
    out[i] = val;
    float sv = val, qv = val * val;
    sv += __shfl_xor(sv, 32); qv += __shfl_xor(qv, 32);
    int lane = tid & 63;
    if (lane < 32) { atomicAdd(&ssum[lane], sv); atomicAdd(&ssq[lane], qv); }
    __syncthreads();
    if (tid < 32) atomicAdd(&stG[tid], ssum[tid]);
    else if (tid < 64) atomicAdd(&stG[32 + tid - 32], ssq[tid - 32]);
}

// k_poolX: BN+ReLU+mask applied on load.
__global__ __launch_bounds__(256) void k_poolX(const float* __restrict__ pt, const float* __restrict__ pp,
                                               const float* __restrict__ st, const float* __restrict__ gam,
                                               const float* __restrict__ bet, const int* __restrict__ nmask,
                                               const int* __restrict__ nmc, float* __restrict__ xg) {
    int i = blockIdx.x * 256 + threadIdx.x;
    if (i >= MM * 32) return;
    int m = i >> 5, ch = i & 31;
    if (!nmask[m]) return;
    float cntf = (float)max(nmc[0], 1);
    float mean = st[ch] / cntf;
    float var = st[32 + ch] / cntf - mean * mean;
    float s = rsqrtf(var + EPSbn) * gam[ch];
    float v = pt[i] * s + (bet[ch] - mean * s);
    v = v > 0.f ? v : 0.f;
    int g = m / NCc;
    int gx = min(max((int)floorf(pp[m * 3] / 30.f), 0), 3);
    int gy = min(max((int)floorf(pp[m * 3 + 1] / 25.f), 0), 3);
    int seg = g * 16 + gy * 4 + gx;
    atomicMax((int*)&xg[seg * 32 + ch], __float_as_int(v));
}

__global__ __launch_bounds__(64) void k_fc(const float* __restrict__ xg, const float* __restrict__ fcw,
                                           float* __restrict__ out) {
    int q = blockIdx.x;          // 50 blocks: (b, o)
    int b = q >> 1, o = q & 1;
    int l = threadIdx.x;
    float a = 0.f;
    for (int k = l; k < 512; k += 64) a += xg[b * 512 + k] * fcw[o * 512 + k];
    for (int s = 32; s; s >>= 1) a += __shfl_xor(a, s);
    if (l == 0) out[b * 2 + o] = a;
}

// ---------------- launcher ----------------

extern "C" void kernel_launch(void* const* d_in, const int* in_sizes, int n_in,
                              void* d_out, int out_size, void* d_ws, size_t ws_size,
                              hipStream_t stream) {
    const float* x_in  = (const float*)d_in[0];
    const float* pos   = (const float*)d_in[1];
    const float* eattr = (const float*)d_in[2];
    const float* w[7];  for (int i = 0; i < 7; i++) w[i]  = (const float*)d_in[3 + i];
    const float* gm[7]; for (int i = 0; i < 7; i++) gm[i] = (const float*)d_in[10 + i];
    const float* bt[7]; for (int i = 0; i < 7; i++) bt[i] = (const float*)d_in[17 + i];
    const float* fcw   = (const float*)d_in[24];
    const int* ei      = (const int*)d_in[25];
    const int* batch   = (const int*)d_in[26];
    const int* esrc = ei;
    const int* edst = ei + NE;
    float* outp = (float*)d_out;

    char* base = (char*)d_ws;
    size_t cur = 0;
    auto alloc = [&](size_t elems) -> void* {
        void* p = base + cur;
        cur += (((elems * 4) + 255) & ~(size_t)255);
        return p;
    };
    // ---- zero-initialized region ----
    int*   deg_i     = (int*)alloc(NN);
    int*   cursor    = (int*)alloc(NN);
    int*   cnt_i     = (int*)alloc(MM);
    float* ppsum     = (float*)alloc(MM * 3);
    unsigned char* presence = (unsigned char*)alloc(PRES / 4);
    float* maxv      = (float*)alloc(64);
    int*   nmc       = (int*)alloc(64);
    int*   dhist     = (int*)alloc(NBK);
    float* st        = (float*)alloc(7 * 64);   // 7 slots: [sum C | sumsq C]
    float* xp_pool   = (float*)alloc(MM * 32);
    float* xg        = (float*)alloc(NBm * 16 * 32);
    size_t zero_bytes = cur;
    // ---- uninitialized region ----
    int*   off_ex    = (int*)alloc(NN);
    int*   bsum      = (int*)alloc(256);
    int*   cluster   = (int*)alloc(NN);
    int*   cluster_p = (int*)alloc(NN);
    int*   dcur      = (int*)alloc(NBK);
    int*   pinv      = (int*)alloc(NN);
    int*   deg_p     = (int*)alloc(NN);
    float* xin_p     = (float*)alloc(NN);
    float4* erec     = (float4*)alloc((size_t)NE * 4);
    float* x_a       = (float*)alloc((size_t)NN * 32);
    float* x_b       = (float*)alloc((size_t)NN * 16);
    float* pp        = (float*)alloc(MM * 3);
    int*   nmask     = (int*)alloc(MM);
    float* ybuf      = (float*)alloc(MM * 256);
    float* pt0       = (float*)alloc(MM * 32);
    float* pt1       = (float*)alloc(MM * 32);
    (void)ws_size; (void)in_sizes; (void)n_in; (void)out_size;

    (void)hipMemsetAsync(d_ws, 0, zero_bytes, stream);

    int gE = (NE + 255) / 256;
    int gN = (NN + 255) / 256;
    int nbS = (NN + 2047) / 2048;

    k_deg<<<gE, 256, 0, stream>>>(edst, deg_i, NE);
    k_dhist<<<gN, 256, 0, stream>>>(deg_i, batch, dhist, NN);
    k_dscan<<<1, 256, 0, stream>>>(dhist, dcur);
    k_dscat<<<gN, 256, 0, stream>>>(deg_i, batch, x_in, dcur, pinv, deg_p, xin_p, NN);
    k_scan1<<<nbS, 256, 0, stream>>>(deg_p, NN, off_ex, bsum);
    k_scan2<<<1, 256, 0, stream>>>(bsum, nbS);
    k_scan3<<<gN, 256, 0, stream>>>(off_ex, NN, bsum);
    k_cluster<<<NBm * 8, 256, 0, stream>>>(pos, pinv, cluster, cluster_p, cnt_i, ppsum);
    k_scatter<<<gE, 256, 0, stream>>>(esrc, edst, eattr, off_ex, pinv, cluster, cursor, erec, presence, NE);
    k_fpp<<<(MM + 255) / 256, 256, 0, stream>>>(cnt_i, ppsum, pp, nmask, nmc);
    k_maxv<<<(PRES + 255) / 256, 256, 0, stream>>>(presence, pp, maxv);

    const float invN = 1.f / (float)NN;
    // mirror-paired wave counts, 4 waves/block (256 threads):
    constexpr int W1 = NBm * ((((BSg + 127) / 128) + 1) / 2);   // TPN=1 -> 1000
    constexpr int W2 = NBm * ((((BSg + 63) / 64) + 1) / 2);     // TPN=2 -> 1975
    constexpr int W4 = NBm * ((((BSg + 31) / 32) + 1) / 2);     // TPN=4 -> 3925
    // conv1: 1 -> 8
    k_conv<1, 8, 1, false><<<(W1 + 3) / 4, 256, 0, stream>>>(xin_p, erec, off_ex, deg_p,
                                                             w[0], nullptr, nullptr, nullptr, 0.f, x_a, st + 0, W1);
    // conv2: 8 -> 16 (BN1+ReLU inline on gather)
    k_conv<8, 16, 2, true><<<(W2 + 3) / 4, 256, 0, stream>>>(x_a, erec, off_ex, deg_p,
                                                             w[1], st + 0, gm[0], bt[0], invN, x_b, st + 64, W2);
    // conv3: 16 -> 16
    k_conv<16, 16, 4, true><<<(W4 + 3) / 4, 256, 0, stream>>>(x_b, erec, off_ex, deg_p,
                                                              w[2], st + 64, gm[1], bt[1], invN, x_a, st + 128, W4);
    // conv4: 16 -> 16
    k_conv<16, 16, 4, true><<<(W4 + 3) / 4, 256, 0, stream>>>(x_a, erec, off_ex, deg_p,
                                                              w[3], st + 128, gm[2], bt[2], invN, x_b, st + 192, W4);
    // conv5: 16 -> 32
    k_conv<16, 32, 4, true><<<(W4 + 3) / 4, 256, 0, stream>>>(x_b, erec, off_ex, deg_p,
                                                              w[4], st + 192, gm[3], bt[3], invN, x_a, st + 256, W4);
    // voxel max pool (BN5+ReLU inline), LDS-staged, permuted space
    k_pool<<<NBm * 8, 256, 0, stream>>>(x_a, cluster_p, st + 256, gm[4], bt[4], invN, xp_pool);
    // conv6 on pooled graph (stats fused into k_convp)
    k_y<<<(MM * 256 + 255) / 256, 256, 0, stream>>>(xp_pool, w[5], ybuf);
    k_convp<<<(MM * 32) / 256, 256, 0, stream>>>(ybuf, pp, presence, maxv, pt0, st + 320);
    // conv7 (BN6+ReLU+mask applied on k_y2 load; stats fused into k_convp)
    k_y2<<<(MM * 256 + 255) / 256, 256, 0, stream>>>(pt0, w[6], st + 320, gm[5], bt[5], nmask, nmc, ybuf);
    k_convp<<<(MM * 32) / 256, 256, 0, stream>>>(ybuf, pp, presence, maxv, pt1, st + 384);
    // MaxPoolingX (BN7+ReLU+mask on load) + FC
    k_poolX<<<(MM * 32 + 255) / 256, 256, 0, stream>>>(pt1, pp, st + 384, gm[6], bt[6], nmask, nmc, xg);
    k_fc<<<50, 64, 0, stream>>>(xg, fcw, outp);
}

// Round 17
// 618.656 us; speedup vs baseline: 1.0861x; 1.0062x over previous
//
#include <hip/hip_runtime.h>

constexpr int NN   = 250000;      // nodes
constexpr int NE   = 1000000;     // edges
constexpr int NBm  = 25;          // graphs
constexpr int BSg  = NN / NBm;    // 10000 nodes per graph
constexpr int NCc  = 72;          // voxel cells per graph
constexpr int MM   = NBm * NCc;   // 1800 pooled slots
constexpr int PRES = NBm * NCc * NCc; // 129600 coarse-edge presence slots
constexpr int NBK  = NBm * 16;    // 400 sort buckets: graph*16 + (15 - min(deg,15))  [descending]
constexpr float EPSbn = 1e-5f;

// ---------------- graph prep ----------------

__global__ __launch_bounds__(256) void k_deg(const int* __restrict__ dst, int* __restrict__ deg, int n) {
    int e = blockIdx.x * 256 + threadIdx.x;
    if (e < n) atomicAdd(&deg[dst[e]], 1);
}

// per-block LDS histogram over 400 (graph,deg) buckets -> low-contention global adds
__global__ __launch_bounds__(256) void k_dhist(const int* __restrict__ deg, const int* __restrict__ batch,
                                               int* __restrict__ dhist, int n) {
    __shared__ int h[NBK];
    int tid = threadIdx.x;
    for (int i = tid; i < NBK; i += 256) h[i] = 0;
    __syncthreads();
    int i = blockIdx.x * 256 + tid;
    if (i < n) atomicAdd(&h[batch[i] * 16 + (15 - min(deg[i], 15))], 1);
    __syncthreads();
    for (int b = tid; b < NBK; b += 256) if (h[b]) atomicAdd(&dhist[b], h[b]);
}

__global__ __launch_bounds__(256) void k_dscan(const int* __restrict__ dhist, int* __restrict__ dcur) {
    __shared__ int tmp[NBK];
    int t = threadIdx.x;
    for (int i = t; i < NBK; i += 256) tmp[i] = dhist[i];
    __syncthreads();
    if (t == 0) { int run = 0; for (int i = 0; i < NBK; i++) { int v = tmp[i]; tmp[i] = run; run += v; } }
    __syncthreads();
    for (int i = t; i < NBK; i += 256) dcur[i] = tmp[i];
}

// two-phase scatter: LDS local ranks + one ranged global atomicAdd per (block,bucket).
__global__ __launch_bounds__(256) void k_dscat(const int* __restrict__ deg, const int* __restrict__ batch,
                                               const float* __restrict__ x_in,
                                               int* __restrict__ dcur, int* __restrict__ pinv,
                                               int* __restrict__ deg_p, float* __restrict__ xin_p, int n) {
    __shared__ int lcnt[NBK];
    __shared__ int gbase[NBK];
    int tid = threadIdx.x;
    for (int i = tid; i < NBK; i += 256) lcnt[i] = 0;
    __syncthreads();
    int i = blockIdx.x * 256 + tid;
    int b = 0, rank = 0;
    if (i < n) {
        b = batch[i] * 16 + (15 - min(deg[i], 15));
        rank = atomicAdd(&lcnt[b], 1);
    }
    __syncthreads();
    for (int k = tid; k < NBK; k += 256)
        if (lcnt[k]) gbase[k] = atomicAdd(&dcur[k], lcnt[k]);
    __syncthreads();
    if (i < n) {
        int slot = gbase[b] + rank;
        pinv[i] = slot;
        deg_p[slot] = deg[i];
        xin_p[slot] = x_in[i];
    }
}

__global__ __launch_bounds__(256) void k_scan1(const int* __restrict__ in, int n,
                                               int* __restrict__ outEx, int* __restrict__ bsum) {
    __shared__ int lds[256];
    int t = threadIdx.x;
    int base = blockIdx.x * 2048;
    int v[8]; int s = 0;
#pragma unroll
    for (int i = 0; i < 8; i++) { int idx = base + t * 8 + i; v[i] = (idx < n) ? in[idx] : 0; s += v[i]; }
    lds[t] = s; __syncthreads();
    for (int o = 1; o < 256; o <<= 1) {
        int x = (t >= o) ? lds[t - o] : 0; __syncthreads();
        lds[t] += x; __syncthreads();
    }
    if (t == 255) bsum[blockIdx.x] = lds[255];
    int run = lds[t] - s;
#pragma unroll
    for (int i = 0; i < 8; i++) { int idx = base + t * 8 + i; if (idx < n) outEx[idx] = run; run += v[i]; }
}

__global__ __launch_bounds__(256) void k_scan2(int* bsum, int nb) {
    __shared__ int l[256];
    int t = threadIdx.x;
    int v = (t < nb) ? bsum[t] : 0;
    l[t] = v; __syncthreads();
    for (int o = 1; o < 256; o <<= 1) {
        int x = (t >= o) ? l[t - o] : 0; __syncthreads();
        l[t] += x; __syncthreads();
    }
    if (t < nb) bsum[t] = l[t] - v;   // exclusive
}

__global__ __launch_bounds__(256) void k_scan3(int* __restrict__ outEx, int n, const int* __restrict__ bsum) {
    int i = blockIdx.x * 256 + threadIdx.x;
    if (i < n) outEx[i] += bsum[i >> 11];
}

// LDS-staged cluster assignment + per-cell count/pos sums.
// Emits pc[i] = {pinv[i], cluster[i]} so k_scatter does ONE int2 gather per
// endpoint instead of two int gathers (half the random cache lines).
__global__ __launch_bounds__(256) void k_cluster(const float* __restrict__ pos, const int* __restrict__ pinv,
                                                 int2* __restrict__ pc, int* __restrict__ cluster_p,
                                                 int* __restrict__ cnt, float* __restrict__ ppsum) {
    __shared__ int lcnt[NCc];
    __shared__ float lpp[NCc * 3];
    int tid = threadIdx.x;
    int g = blockIdx.x >> 3, part = blockIdx.x & 7;
    for (int i = tid; i < NCc; i += 256) lcnt[i] = 0;
    for (int i = tid; i < NCc * 3; i += 256) lpp[i] = 0.f;
    __syncthreads();
    int base = g * BSg + part * (BSg / 8);
    int lim = BSg / 8;
    for (int k = tid; k < lim; k += 256) {
        int i = base + k;
        float px = pos[i * 3], py = pos[i * 3 + 1], pz = pos[i * 3 + 2];
        int cx = min(max((int)floorf(px / 16.f), 0), 7);
        int cy = min(max((int)floorf(py / 12.f), 0), 8);
        int lc = cy * 8 + cx;
        int pv = pinv[i];
        pc[i] = make_int2(pv, g * NCc + lc);
        cluster_p[pv] = g * NCc + lc;
        atomicAdd(&lcnt[lc], 1);
        atomicAdd(&lpp[lc * 3 + 0], px);
        atomicAdd(&lpp[lc * 3 + 1], py);
        atomicAdd(&lpp[lc * 3 + 2], pz);
    }
    __syncthreads();
    for (int c = tid; c < NCc; c += 256) {
        if (lcnt[c]) {
            atomicAdd(&cnt[g * NCc + c], lcnt[c]);
            atomicAdd(&ppsum[(g * NCc + c) * 3 + 0], lpp[c * 3 + 0]);
            atomicAdd(&ppsum[(g * NCc + c) * 3 + 1], lpp[c * 3 + 1]);
            atomicAdd(&ppsum[(g * NCc + c) * 3 + 2], lpp[c * 3 + 2]);
        }
    }
}

// Fused edge scatter + coarse presence; 2 edges per thread with interleaved
// loads (doubled memory-level parallelism in this latency-bound kernel).
__global__ __launch_bounds__(256) void k_scatter(const int* __restrict__ src, const int* __restrict__ dst,
                                                 const float* __restrict__ ea, const int* __restrict__ offx,
                                                 const int2* __restrict__ pc,
                                                 int* __restrict__ cursor, float4* __restrict__ erec,
                                                 unsigned char* __restrict__ presence, int n) {
    int e0 = blockIdx.x * 512 + threadIdx.x;
    int e1 = e0 + 256;
    bool v0 = e0 < n, v1 = e1 < n;
    int s0 = 0, d0 = 0, s1 = 0, d1 = 0;
    if (v0) { s0 = src[e0]; d0 = dst[e0]; }
    if (v1) { s1 = src[e1]; d1 = dst[e1]; }
    int2 pcs0, pcd0, pcs1, pcd1;
    pcs0 = v0 ? pc[s0] : make_int2(0, 0);
    pcd0 = v0 ? pc[d0] : make_int2(0, 0);
    pcs1 = v1 ? pc[s1] : make_int2(0, 0);
    pcd1 = v1 ? pc[d1] : make_int2(0, 0);
    float a0x = 0, a0y = 0, a0z = 0, a1x = 0, a1y = 0, a1z = 0;
    if (v0) { a0x = ea[e0 * 3]; a0y = ea[e0 * 3 + 1]; a0z = ea[e0 * 3 + 2]; }
    if (v1) { a1x = ea[e1 * 3]; a1y = ea[e1 * 3 + 1]; a1z = ea[e1 * 3 + 2]; }
    if (v0) {
        int j = offx[pcd0.x] + atomicAdd(&cursor[pcd0.x], 1);
        erec[j] = make_float4(__int_as_float(pcs0.x),
                              fminf(fmaxf(a0x, 0.f), 1.f),
                              fminf(fmaxf(a0y, 0.f), 1.f),
                              fminf(fmaxf(a0z, 0.f), 1.f));
        if (pcs0.y != pcd0.y) {
            int g = pcs0.y / NCc;
            presence[g * (NCc * NCc) + (pcs0.y % NCc) * NCc + (pcd0.y % NCc)] = 1;
        }
    }
    if (v1) {
        int j = offx[pcd1.x] + atomicAdd(&cursor[pcd1.x], 1);
        erec[j] = make_float4(__int_as_float(pcs1.x),
                              fminf(fmaxf(a1x, 0.f), 1.f),
                              fminf(fmaxf(a1y, 0.f), 1.f),
                              fminf(fmaxf(a1z, 0.f), 1.f));
        if (pcs1.y != pcd1.y) {
            int g = pcs1.y / NCc;
            presence[g * (NCc * NCc) + (pcs1.y % NCc) * NCc + (pcd1.y % NCc)] = 1;
        }
    }
}

__global__ __launch_bounds__(256) void k_fpp(const int* __restrict__ cnt, const float* __restrict__ ppsum,
                                             float* __restrict__ pp, int* __restrict__ nmask, int* __restrict__ nmc) {
    int m = blockIdx.x * 256 + threadIdx.x;
    if (m >= MM) return;
    int c = cnt[m];
    float inv = 1.f / (float)max(c, 1);
    pp[m * 3 + 0] = ppsum[m * 3 + 0] * inv;
    pp[m * 3 + 1] = ppsum[m * 3 + 1] * inv;
    pp[m * 3 + 2] = ppsum[m * 3 + 2] * inv;
    nmask[m] = (c > 0);
    if (c > 0) atomicAdd(nmc, 1);
}

__global__ __launch_bounds__(256) void k_maxv(const unsigned char* __restrict__ presence, const float* __restrict__ pp,
                                              float* __restrict__ maxv) {
    int i = blockIdx.x * 256 + threadIdx.x;
    float m = 0.f;
    if (i < PRES && presence[i]) {
        int g = i / (NCc * NCc), rem = i % (NCc * NCc);
        int r = g * NCc + rem / NCc, c = g * NCc + rem % NCc;
        float d0 = fabsf(pp[c * 3 + 0] - pp[r * 3 + 0]);
        float d1 = fabsf(pp[c * 3 + 1] - pp[r * 3 + 1]);
        float d2 = fabsf(pp[c * 3 + 2] - pp[r * 3 + 2]);
        m = fmaxf(fmaxf(d0, d1), d2);
    }
    for (int o = 32; o; o >>= 1) m = fmaxf(m, __shfl_xor(m, o));
    if ((threadIdx.x & 63) == 0) atomicMax((int*)maxv, __float_as_int(m));
}

// ---------------- full-graph spline conv ----------------
// R12/R13 exact configuration (measured best: 74.0us for conv5):
// mirror-paired balanced waves (R=2), 256-thread blocks, depth-1 pipelined
// branchless edge loop.

template <int CIN, int COUT, int TPN, bool BN>
__global__ __launch_bounds__(256) void k_conv(
    const float* __restrict__ x, const float4* __restrict__ erec,
    const int* __restrict__ off, const int* __restrict__ deg,
    const float* __restrict__ W, const float* __restrict__ st,
    const float* __restrict__ gam, const float* __restrict__ bet, float invcnt,
    float* __restrict__ out, float* __restrict__ stG, int nwaves) {
    constexpr int CPT = CIN / TPN;
    constexpr int SLICE = COUT + 4;          // t-rows land on disjoint banks
    constexpr int NPW = 128 / TPN;           // nodes per wave per chunk (R=2)
    constexpr int CPG = (BSg + NPW - 1) / NPW;
    constexpr int WPG = (CPG + 1) / 2;
    constexpr int NH = (COUT > 16) ? 2 : 1;
    constexpr int OH = COUT / NH;            // output-half width
    constexpr int CWH = OH / TPN;
    __shared__ float Ws[8 * CIN * SLICE];
    __shared__ float ssum[COUT], ssq[COUT];
    int tid = threadIdx.x;
    for (int idx = tid; idx < 8 * CIN * COUT; idx += 256) {
        int s = idx / (CIN * COUT), r = idx % (CIN * COUT);
        int ci = r / COUT, co = r % COUT;
        int t_ = ci / CPT, i_ = ci % CPT;
        Ws[((s * CPT + i_) * TPN + t_) * SLICE + co] = W[idx];
    }
    if (tid < COUT) { ssum[tid] = 0.f; ssq[tid] = 0.f; }
    __syncthreads();

    int w = blockIdx.x * 4 + (tid >> 6);
    int lane = tid & 63;
    int t = lane & (TPN - 1);
    int qi = lane / TPN;
    bool wact = (w < nwaves);
    int g = wact ? (w / WPG) : 0;
    int p = wact ? (w % WPG) : 0;

    float sc[CPT], sh[CPT];
    if constexpr (BN) {
#pragma unroll
        for (int i = 0; i < CPT; i++) {
            int c = t * CPT + i;
            float mean = st[c] * invcnt;
            float var = st[CIN + c] * invcnt - mean * mean;
            float s = rsqrtf(var + EPSbn) * gam[c];
            sc[i] = s; sh[i] = bet[c] - mean * s;
        }
    }

    for (int rep = 0; rep < 2; rep++) {
        if (!wact) break;
        int c = rep ? (CPG - 1 - p) : p;
        if (rep && c == p) break;              // odd CPG middle chunk: do once
        int base = g * BSg + c * NPW;
        int lim = min(NPW, BSg - c * NPW);
        int no = 2 * qi;
        bool act = no < lim;
        int n0 = base + no;

        float agg[2][8 * CPT];
#pragma unroll
        for (int r = 0; r < 2; r++)
#pragma unroll
            for (int i = 0; i < 8 * CPT; i++) agg[r][i] = 0.f;

        int dg0 = 0, dg1 = 0, jb0 = 0, jb1 = 0;
        if (act) {
            jb0 = off[n0];     dg0 = deg[n0];
            jb1 = off[n0 + 1]; dg1 = deg[n0 + 1];
        }
        int mx = max(dg0, dg1);
        int cl0 = max(dg0 - 1, 0), cl1 = max(dg1 - 1, 0);
        float4 rec0 = erec[min(jb0, NE - 1)];
        float4 rec1 = erec[min(jb1, NE - 1)];
        for (int m = 0; m < mx; m++) {
            int s0 = __float_as_int(rec0.x);
            int s1 = __float_as_int(rec1.x);
            const float* xs0 = &x[(size_t)s0 * CIN + t * CPT];
            const float* xs1 = &x[(size_t)s1 * CIN + t * CPT];
            float xv0[CPT], xv1[CPT];
            if constexpr (CPT == 4) {
                float4 v0 = *(const float4*)xs0;
                float4 v1 = *(const float4*)xs1;
                xv0[0] = v0.x; xv0[1] = v0.y; xv0[2] = v0.z; xv0[3] = v0.w;
                xv1[0] = v1.x; xv1[1] = v1.y; xv1[2] = v1.z; xv1[3] = v1.w;
            } else if constexpr (CPT == 8) {
#pragma unroll
                for (int i = 0; i < 8; i += 4) {
                    float4 v0 = *(const float4*)&xs0[i];
                    float4 v1 = *(const float4*)&xs1[i];
                    xv0[i] = v0.x; xv0[i + 1] = v0.y; xv0[i + 2] = v0.z; xv0[i + 3] = v0.w;
                    xv1[i] = v1.x; xv1[i + 1] = v1.y; xv1[i + 2] = v1.z; xv1[i + 3] = v1.w;
                }
            } else {
#pragma unroll
                for (int i = 0; i < CPT; i++) { xv0[i] = xs0[i]; xv1[i] = xs1[i]; }
            }
            float4 nrec0 = erec[jb0 + min(m + 1, cl0)];
            float4 nrec1 = erec[jb1 + min(m + 1, cl1)];
            float f0 = (m < dg0) ? 1.f : 0.f;
            float f1 = (m < dg1) ? 1.f : 0.f;
            if constexpr (BN) {
#pragma unroll
                for (int i = 0; i < CPT; i++) {
                    float a = xv0[i] * sc[i] + sh[i]; xv0[i] = a > 0.f ? a : 0.f;
                    float b = xv1[i] * sc[i] + sh[i]; xv1[i] = b > 0.f ? b : 0.f;
                }
            }
            {
                float p0 = rec0.y, p1 = rec0.z;
                float p2 = rec0.w * f0, q2 = (1.f - rec0.w) * f0;
                float q0 = 1.f - p0, q1 = 1.f - p1;
                float a00 = q0 * q1, a10 = p0 * q1, a01 = q0 * p1, a11 = p0 * p1;
                float bbv[8] = {a00 * q2, a10 * q2, a01 * q2, a11 * q2,
                                a00 * p2, a10 * p2, a01 * p2, a11 * p2};
#pragma unroll
                for (int k = 0; k < 8; k++)
#pragma unroll
                    for (int i = 0; i < CPT; i++) agg[0][k * CPT + i] += bbv[k] * xv0[i];
            }
            {
                float p0 = rec1.y, p1 = rec1.z;
                float p2 = rec1.w * f1, q2 = (1.f - rec1.w) * f1;
                float q0 = 1.f - p0, q1 = 1.f - p1;
                float a00 = q0 * q1, a10 = p0 * q1, a01 = q0 * p1, a11 = p0 * p1;
                float bbv[8] = {a00 * q2, a10 * q2, a01 * q2, a11 * q2,
                                a00 * p2, a10 * p2, a01 * p2, a11 * p2};
#pragma unroll
                for (int k = 0; k < 8; k++)
#pragma unroll
                    for (int i = 0; i < CPT; i++) agg[1][k * CPT + i] += bbv[k] * xv1[i];
            }
            rec0 = nrec0; rec1 = nrec1;
        }

        float inv0 = 1.f / (float)max(dg0, 1);
        float inv1 = 1.f / (float)max(dg1, 1);

#pragma unroll
        for (int h = 0; h < NH; h++) {
            float o0[OH], o1[OH];
#pragma unroll
            for (int c2 = 0; c2 < OH; c2++) { o0[c2] = 0.f; o1[c2] = 0.f; }
#pragma unroll
            for (int k = 0; k < 8; k++)
#pragma unroll
                for (int i = 0; i < CPT; i++) {
                    float a0 = agg[0][k * CPT + i];
                    float a1 = agg[1][k * CPT + i];
                    const float4* wr = (const float4*)&Ws[((k * CPT + i) * TPN + t) * SLICE + h * OH];
#pragma unroll
                    for (int c2 = 0; c2 < OH / 4; c2++) {
                        float4 wv = wr[c2];
                        o0[4 * c2 + 0] += a0 * wv.x; o0[4 * c2 + 1] += a0 * wv.y;
                        o0[4 * c2 + 2] += a0 * wv.z; o0[4 * c2 + 3] += a0 * wv.w;
                        o1[4 * c2 + 0] += a1 * wv.x; o1[4 * c2 + 1] += a1 * wv.y;
                        o1[4 * c2 + 2] += a1 * wv.z; o1[4 * c2 + 3] += a1 * wv.w;
                    }
                }
#pragma unroll
            for (int m = 1; m < TPN; m <<= 1)
#pragma unroll
                for (int c2 = 0; c2 < OH; c2++) { o0[c2] += __shfl_xor(o0[c2], m); o1[c2] += __shfl_xor(o1[c2], m); }

            float v0[CWH], v1[CWH], sv[CWH], qv[CWH];
#pragma unroll
            for (int c2 = 0; c2 < CWH; c2++) {
                v0[c2] = act ? o0[t * CWH + c2] * inv0 : 0.f;
                v1[c2] = act ? o1[t * CWH + c2] * inv1 : 0.f;
                sv[c2] = v0[c2] + v1[c2];
                qv[c2] = v0[c2] * v0[c2] + v1[c2] * v1[c2];
            }
            if (act) {
                float* op0 = &out[(size_t)n0 * COUT + h * OH + t * CWH];
                float* op1 = op0 + COUT;
#pragma unroll
                for (int c2 = 0; c2 < CWH; c2++) { op0[c2] = v0[c2]; op1[c2] = v1[c2]; }
            }
#pragma unroll
            for (int m = TPN; m < 64; m <<= 1)
#pragma unroll
                for (int c2 = 0; c2 < CWH; c2++) { sv[c2] += __shfl_xor(sv[c2], m); qv[c2] += __shfl_xor(qv[c2], m); }
            if (lane < TPN) {
#pragma unroll
                for (int c2 = 0; c2 < CWH; c2++) {
                    atomicAdd(&ssum[h * OH + t * CWH + c2], sv[c2]);
                    atomicAdd(&ssq[h * OH + t * CWH + c2], qv[c2]);
                }
            }
        }
    }
    __syncthreads();
    if (tid < COUT) atomicAdd(&stG[tid], ssum[tid]);
    else if (tid < 2 * COUT) atomicAdd(&stG[tid], ssq[tid - COUT]);
}

// ---------------- voxel max pool (permuted space, BN5+ReLU inline) ----------------
__global__ __launch_bounds__(256) void k_pool(const float* __restrict__ x, const int* __restrict__ cluster_p,
                                              const float* __restrict__ st, const float* __restrict__ gam,
                                              const float* __restrict__ bet, float invcnt,
                                              float* __restrict__ xp) {
    __shared__ float cellv[NCc * 32];
    __shared__ float scs[32], shs[32];
    int tid = threadIdx.x;
    int g = blockIdx.x >> 3, part = blockIdx.x & 7;
    for (int i = tid; i < NCc * 32; i += 256) cellv[i] = 0.f;
    if (tid < 32) {
        float mean = st[tid] * invcnt;
        float var = st[32 + tid] * invcnt - mean * mean;
        float s = rsqrtf(var + EPSbn) * gam[tid];
        scs[tid] = s; shs[tid] = bet[tid] - mean * s;
    }
    __syncthreads();
    int base = g * BSg + part * (BSg / 8);
    const int nelem = (BSg / 8) * 32;
    for (int ii = tid; ii < nelem; ii += 256) {
        int nd = base + (ii >> 5), ch = ii & 31;
        float v = x[(size_t)nd * 32 + ch] * scs[ch] + shs[ch];
        v = v > 0.f ? v : 0.f;
        int lc = cluster_p[nd] - g * NCc;
        atomicMax((int*)&cellv[lc * 32 + ch], __float_as_int(v));
    }
    __syncthreads();
    for (int ii = tid; ii < NCc * 32; ii += 256)
        atomicMax((int*)&xp[g * NCc * 32 + ii], __float_as_int(cellv[ii]));
}

// ---------------- pooled convs ----------------
__global__ __launch_bounds__(256) void k_y(const float* __restrict__ xp, const float* __restrict__ W,
                                           float* __restrict__ y) {
    int i = blockIdx.x * 256 + threadIdx.x;
    if (i >= MM * 256) return;
    int r = i >> 8, rem = i & 255, s = rem >> 5, co = rem & 31;
    const float* xr = &xp[r * 32];
    const float* w = &W[s * 1024 + co];
    float a = 0.f;
#pragma unroll
    for (int ci = 0; ci < 32; ci++) a += xr[ci] * w[ci * 32];
    y[i] = a;
}

// k_y2: BN+ReLU+mask applied on load.
__global__ __launch_bounds__(256) void k_y2(const float* __restrict__ pt, const float* __restrict__ W,
                                            const float* __restrict__ st, const float* __restrict__ gam,
                                            const float* __restrict__ bet, const int* __restrict__ nmask,
                                            const int* __restrict__ nmc, float* __restrict__ y) {
    __shared__ float scs[32], shs[32];
    int tid = threadIdx.x;
    if (tid < 32) {
        float cntf = (float)max(nmc[0], 1);
        float mean = st[tid] / cntf;
        float var = st[32 + tid] / cntf - mean * mean;
        float s = rsqrtf(var + EPSbn) * gam[tid];
        scs[tid] = s; shs[tid] = bet[tid] - mean * s;
    }
    __syncthreads();
    int i = blockIdx.x * 256 + tid;
    if (i >= MM * 256) return;
    int r = i >> 8, rem = i & 255, s = rem >> 5, co = rem & 31;
    float a = 0.f;
    if (nmask[r]) {
        const float* xr = &pt[r * 32];
        const float* w = &W[s * 1024 + co];
#pragma unroll
        for (int ci = 0; ci < 32; ci++) {
            float v = xr[ci] * scs[ci] + shs[ci];
            v = v > 0.f ? v : 0.f;
            a += v * w[ci * 32];
        }
    }
    y[i] = a;
}

// k_convp with fused output stats (sum/sumsq per channel -> stG).
__global__ __launch_bounds__(256) void k_convp(const float* __restrict__ y, const float* __restrict__ pp,
                                               const unsigned char* __restrict__ presence,
                                               const float* __restrict__ maxv, float* __restrict__ out,
                                               float* __restrict__ stG) {
    __shared__ float ssum[32], ssq[32];
    int tid = threadIdx.x;
    if (tid < 32) { ssum[tid] = 0.f; ssq[tid] = 0.f; }
    __syncthreads();
    int i = blockIdx.x * 256 + tid;       // grid is exactly MM*32 = 225 blocks
    int c = i >> 5, co = i & 31;
    int g = c / NCc, lc = c % NCc;
    float mv = fmaxf(maxv[0], 1e-9f);
    float inv2 = 0.5f / mv;
    float pcx = pp[c * 3], pcy = pp[c * 3 + 1], pcz = pp[c * 3 + 2];
    const unsigned char* pr = &presence[g * (NCc * NCc) + lc];
    float acc = 0.f; int dg = 0;
    for (int lr = 0; lr < NCc; lr++) {
        if (pr[lr * NCc]) {
            dg++;
            int r = g * NCc + lr;
            float p0 = fminf(fmaxf((pcx - pp[r * 3]) * inv2 + 0.5f, 0.f), 1.f);
            float p1 = fminf(fmaxf((pcy - pp[r * 3 + 1]) * inv2 + 0.5f, 0.f), 1.f);
            float p2 = fminf(fmaxf((pcz - pp[r * 3 + 2]) * inv2 + 0.5f, 0.f), 1.f);
            float q0 = 1.f - p0, q1 = 1.f - p1, q2 = 1.f - p2;
            const float* yr = &y[r * 256 + co];
            acc += (q0 * q1 * q2) * yr[0]   + (p0 * q1 * q2) * yr[32]
                 + (q0 * p1 * q2) * yr[64]  + (p0 * p1 * q2) * yr[96]
                 + (q0 * q1 * p2) * yr[128] + (p0 * q1 * p2) * yr[160]
                 + (q0 * p1 * p2) * yr[192] + (p0 * p1 * p2) * yr[224];
        }
    }
    float val = acc / (float)max(dg, 1);
    out[i] = val;
    float sv = val, qv = val * val;
    sv += __shfl_xor(sv, 32); qv += __shfl_xor(qv, 32);
    int lane = tid & 63;
    if (lane < 32) { atomicAdd(&ssum[lane], sv); atomicAdd(&ssq[lane], qv); }
    __syncthreads();
    if (tid < 32) atomicAdd(&stG[tid], ssum[tid]);
    else if (tid < 64) atomicAdd(&stG[32 + tid - 32], ssq[tid - 32]);
}

// k_poolX: BN+ReLU+mask applied on load.
__global__ __launch_bounds__(256) void k_poolX(const float* __restrict__ pt, const float* __restrict__ pp,
                                               const float* __restrict__ st, const float* __restrict__ gam,
                                               const float* __restrict__ bet, const int* __restrict__ nmask,
                                               const int* __restrict__ nmc, float* __restrict__ xg) {
    int i = blockIdx.x * 256 + threadIdx.x;
    if (i >= MM * 32) return;
    int m = i >> 5, ch = i & 31;
    if (!nmask[m]) return;
    float cntf = (float)max(nmc[0], 1);
    float mean = st[ch] / cntf;
    float var = st[32 + ch] / cntf - mean * mean;
    float s = rsqrtf(var + EPSbn) * gam[ch];
    float v = pt[i] * s + (bet[ch] - mean * s);
    v = v > 0.f ? v : 0.f;
    int g = m / NCc;
    int gx = min(max((int)floorf(pp[m * 3] / 30.f), 0), 3);
    int gy = min(max((int)floorf(pp[m * 3 + 1] / 25.f), 0), 3);
    int seg = g * 16 + gy * 4 + gx;
    atomicMax((int*)&xg[seg * 32 + ch], __float_as_int(v));
}

__global__ __launch_bounds__(64) void k_fc(const float* __restrict__ xg, const float* __restrict__ fcw,
                                           float* __restrict__ out) {
    int q = blockIdx.x;          // 50 blocks: (b, o)
    int b = q >> 1, o = q & 1;
    int l = threadIdx.x;
    float a = 0.f;
    for (int k = l; k < 512; k += 64) a += xg[b * 512 + k] * fcw[o * 512 + k];
    for (int s = 32; s; s >>= 1) a += __shfl_xor(a, s);
    if (l == 0) out[b * 2 + o] = a;
}

// ---------------- launcher ----------------

extern "C" void kernel_launch(void* const* d_in, const int* in_sizes, int n_in,
                              void* d_out, int out_size, void* d_ws, size_t ws_size,
                              hipStream_t stream) {
    const float* x_in  = (const float*)d_in[0];
    const float* pos   = (const float*)d_in[1];
    const float* eattr = (const float*)d_in[2];
    const float* w[7];  for (int i = 0; i < 7; i++) w[i]  = (const float*)d_in[3 + i];
    const float* gm[7]; for (int i = 0; i < 7; i++) gm[i] = (const float*)d_in[10 + i];
    const float* bt[7]; for (int i = 0; i < 7; i++) bt[i] = (const float*)d_in[17 + i];
    const float* fcw   = (const float*)d_in[24];
    const int* ei      = (const int*)d_in[25];
    const int* batch   = (const int*)d_in[26];
    const int* esrc = ei;
    const int* edst = ei + NE;
    float* outp = (float*)d_out;

    char* base = (char*)d_ws;
    size_t cur = 0;
    auto alloc = [&](size_t elems) -> void* {
        void* p = base + cur;
        cur += (((elems * 4) + 255) & ~(size_t)255);
        return p;
    };
    // ---- zero-initialized region ----
    int*   deg_i     = (int*)alloc(NN);
    int*   cursor    = (int*)alloc(NN);
    int*   cnt_i     = (int*)alloc(MM);
    float* ppsum     = (float*)alloc(MM * 3);
    unsigned char* presence = (unsigned char*)alloc(PRES / 4);
    float* maxv      = (float*)alloc(64);
    int*   nmc       = (int*)alloc(64);
    int*   dhist     = (int*)alloc(NBK);
    float* st        = (float*)alloc(7 * 64);   // 7 slots: [sum C | sumsq C]
    float* xp_pool   = (float*)alloc(MM * 32);
    float* xg        = (float*)alloc(NBm * 16 * 32);
    size_t zero_bytes = cur;
    // ---- uninitialized region ----
    int*   off_ex    = (int*)alloc(NN);
    int*   bsum      = (int*)alloc(256);
    int2*  pc        = (int2*)alloc((size_t)NN * 2);
    int*   cluster_p = (int*)alloc(NN);
    int*   dcur      = (int*)alloc(NBK);
    int*   pinv      = (int*)alloc(NN);
    int*   deg_p     = (int*)alloc(NN);
    float* xin_p     = (float*)alloc(NN);
    float4* erec     = (float4*)alloc((size_t)NE * 4);
    float* x_a       = (float*)alloc((size_t)NN * 32);
    float* x_b       = (float*)alloc((size_t)NN * 16);
    float* pp        = (float*)alloc(MM * 3);
    int*   nmask     = (int*)alloc(MM);
    float* ybuf      = (float*)alloc(MM * 256);
    float* pt0       = (float*)alloc(MM * 32);
    float* pt1       = (float*)alloc(MM * 32);
    (void)ws_size; (void)in_sizes; (void)n_in; (void)out_size;

    (void)hipMemsetAsync(d_ws, 0, zero_bytes, stream);

    int gE = (NE + 255) / 256;
    int gN = (NN + 255) / 256;
    int nbS = (NN + 2047) / 2048;

    k_deg<<<gE, 256, 0, stream>>>(edst, deg_i, NE);
    k_dhist<<<gN, 256, 0, stream>>>(deg_i, batch, dhist, NN);
    k_dscan<<<1, 256, 0, stream>>>(dhist, dcur);
    k_dscat<<<gN, 256, 0, stream>>>(deg_i, batch, x_in, dcur, pinv, deg_p, xin_p, NN);
    k_scan1<<<nbS, 256, 0, stream>>>(deg_p, NN, off_ex, bsum);
    k_scan2<<<1, 256, 0, stream>>>(bsum, nbS);
    k_scan3<<<gN, 256, 0, stream>>>(off_ex, NN, bsum);
    k_cluster<<<NBm * 8, 256, 0, stream>>>(pos, pinv, pc, cluster_p, cnt_i, ppsum);
    k_scatter<<<(NE + 511) / 512, 256, 0, stream>>>(esrc, edst, eattr, off_ex, pc, cursor, erec, presence, NE);
    k_fpp<<<(MM + 255) / 256, 256, 0, stream>>>(cnt_i, ppsum, pp, nmask, nmc);
    k_maxv<<<(PRES + 255) / 256, 256, 0, stream>>>(presence, pp, maxv);

    const float invN = 1.f / (float)NN;
    // mirror-paired wave counts, 4 waves/block (256 threads):
    constexpr int W1 = NBm * ((((BSg + 127) / 128) + 1) / 2);   // TPN=1 -> 1000
    constexpr int W2 = NBm * ((((BSg + 63) / 64) + 1) / 2);     // TPN=2 -> 1975
    constexpr int W4 = NBm * ((((BSg + 31) / 32) + 1) / 2);     // TPN=4 -> 3925
    // conv1: 1 -> 8
    k_conv<1, 8, 1, false><<<(W1 + 3) / 4, 256, 0, stream>>>(xin_p, erec, off_ex, deg_p,
                                                             w[0], nullptr, nullptr, nullptr, 0.f, x_a, st + 0, W1);
    // conv2: 8 -> 16 (BN1+ReLU inline on gather)
    k_conv<8, 16, 2, true><<<(W2 + 3) / 4, 256, 0, stream>>>(x_a, erec, off_ex, deg_p,
                                                             w[1], st + 0, gm[0], bt[0], invN, x_b, st + 64, W2);
    // conv3: 16 -> 16
    k_conv<16, 16, 4, true><<<(W4 + 3) / 4, 256, 0, stream>>>(x_b, erec, off_ex, deg_p,
                                                              w[2], st + 64, gm[1], bt[1], invN, x_a, st + 128, W4);
    // conv4: 16 -> 16
    k_conv<16, 16, 4, true><<<(W4 + 3) / 4, 256, 0, stream>>>(x_a, erec, off_ex, deg_p,
                                                              w[3], st + 128, gm[2], bt[2], invN, x_b, st + 192, W4);
    // conv5: 16 -> 32
    k_conv<16, 32, 4, true><<<(W4 + 3) / 4, 256, 0, stream>>>(x_b, erec, off_ex, deg_p,
                                                              w[4], st + 192, gm[3], bt[3], invN, x_a, st + 256, W4);
    // voxel max pool (BN5+ReLU inline), LDS-staged, permuted space
    k_pool<<<NBm * 8, 256, 0, stream>>>(x_a, cluster_p, st + 256, gm[4], bt[4], invN, xp_pool);
    // conv6 on pooled graph (stats fused into k_convp)
    k_y<<<(MM * 256 + 255) / 256, 256, 0, stream>>>(xp_pool, w[5], ybuf);
    k_convp<<<(MM * 32) / 256, 256, 0, stream>>>(ybuf, pp, presence, maxv, pt0, st + 320);
    // conv7 (BN6+ReLU+mask applied on k_y2 load; stats fused into k_convp)
    k_y2<<<(MM * 256 + 255) / 256, 256, 0, stream>>>(pt0, w[6], st + 320, gm[5], bt[5], nmask, nmc, ybuf);
    k_convp<<<(MM * 32) / 256, 256, 0, stream>>>(ybuf, pp, presence, maxv, pt1, st + 384);
    // MaxPoolingX (BN7+ReLU+mask on load) + FC
    k_poolX<<<(MM * 32 + 255) / 256, 256, 0, stream>>>(pt1, pp, st + 384, gm[6], bt[6], nmask, nmc, xg);
    k_fc<<<50, 64, 0, stream>>>(xg, fcw, outp);
}